// Round 1
// baseline (1058.432 us; speedup 1.0000x reference)
//
#include <hip/hip_runtime.h>
#include <cstdint>

// ---------------------------------------------------------------------------
// TransformerBlock: LN1 -> qdq -> QKV gemms -> attn(relpos bias) -> Wo gemm
//  -> +resid -> LN2 -> W1 gemm -> gelu(tanh) -> W2 gemm.
// Per-tensor int8 QDQ on every GEMM input (activations and weights).
// bf16 MFMA (16x16x32) for all GEMMs; fp32 for LN/softmax/residual/absmax.
// ---------------------------------------------------------------------------

typedef unsigned short u16;
typedef __bf16 bf16x8 __attribute__((ext_vector_type(8)));
typedef float  f32x4  __attribute__((ext_vector_type(4)));

#define MFMA(a, b, c) __builtin_amdgcn_mfma_f32_16x16x32_bf16(a, b, c, 0, 0, 0)

__device__ __forceinline__ float bf2f(u16 h) {
    return __uint_as_float(((unsigned)h) << 16);
}
__device__ __forceinline__ u16 f2bf(float f) {   // RNE
    unsigned u = __float_as_uint(f);
    u += 0x7FFFu + ((u >> 16) & 1u);
    return (u16)(u >> 16);
}
__device__ __forceinline__ float qdqv(float v, float s) {
    float q = rintf(v / s);                       // rint = RNE, matches jnp.round
    q = fminf(fmaxf(q, -127.f), 127.f);
    return q * s;
}
__device__ __forceinline__ float getscale(const int* scales, int slot) {
    float amax = __int_as_float(scales[slot]);
    return fmaxf(amax / 127.f, 1e-8f);
}

// global -> LDS direct (16B per lane; LDS dest is wave-uniform base + lane*16)
typedef const __attribute__((address_space(1))) unsigned gas_u32;
typedef __attribute__((address_space(3))) unsigned las_u32;
__device__ __forceinline__ void gld16(const void* g, void* l) {
    __builtin_amdgcn_global_load_lds((gas_u32*)g, (las_u32*)l, 16, 0, 0);
}

// ---------------------------------------------------------------------------
__global__ void zero_k(int* s) {
    if (threadIdx.x < 16) s[threadIdx.x] = 0;
}

// grid-stride absmax of an fp32 tensor -> scales[slot] (float bits via int max)
__global__ void wabsmax_k(const float* __restrict__ w, int n, int* scales, int slot) {
    float m = 0.f;
    for (int i = blockIdx.x * blockDim.x + threadIdx.x; i < n; i += gridDim.x * blockDim.x)
        m = fmaxf(m, fabsf(w[i]));
#pragma unroll
    for (int o = 32; o > 0; o >>= 1) m = fmaxf(m, __shfl_xor(m, o));
    if ((threadIdx.x & 63) == 0) atomicMax(scales + slot, __float_as_int(m));
}

// quantize (qdq) + transpose weight: W[K][N] fp32 -> Wt[N][K] bf16
__global__ __launch_bounds__(256) void wqt_k(const float* __restrict__ W, u16* __restrict__ Wt,
                                             int K, int N, const int* __restrict__ scales, int slot) {
    __shared__ float t[32][33];
    const int n0 = blockIdx.x * 32, k0 = blockIdx.y * 32;
    const float s = getscale(scales, slot);
    const int c = threadIdx.x & 31, r0 = threadIdx.x >> 5;   // 8 rows per pass
#pragma unroll
    for (int i = 0; i < 4; i++) {
        int kk = k0 + r0 + i * 8;
        t[r0 + i * 8][c] = qdqv(W[(long)kk * N + n0 + c], s);
    }
    __syncthreads();
#pragma unroll
    for (int i = 0; i < 4; i++) {
        int nn = n0 + r0 + i * 8;
        Wt[(long)nn * K + k0 + c] = f2bf(t[c][r0 + i * 8]);
    }
}

// block reduction helper (256 threads, 4 waves)
__device__ __forceinline__ float blk_sum(float v, float* red) {
#pragma unroll
    for (int o = 32; o > 0; o >>= 1) v += __shfl_xor(v, o);
    __syncthreads();
    if ((threadIdx.x & 63) == 0) red[threadIdx.x >> 6] = v;
    __syncthreads();
    return red[0] + red[1] + red[2] + red[3];
}

// LayerNorm (eps=1e-6): fp32 in -> bf16 out (raw, pre-qdq), absmax -> slot
__global__ __launch_bounds__(256) void ln_k(const float* __restrict__ in, const float* __restrict__ gam,
                                            const float* __restrict__ bet, u16* __restrict__ out,
                                            int* __restrict__ scales, int slot) {
    __shared__ float red[4];
    const long row = blockIdx.x;
    const int tid = threadIdx.x;
    float4 v = ((const float4*)(in + row * 1024))[tid];
    float mean = blk_sum(v.x + v.y + v.z + v.w, red) * (1.f / 1024.f);
    float dx = v.x - mean, dy = v.y - mean, dz = v.z - mean, dw = v.w - mean;
    float var = blk_sum(dx * dx + dy * dy + dz * dz + dw * dw, red) * (1.f / 1024.f);
    float inv = rsqrtf(var + 1e-6f);
    float4 gg = ((const float4*)gam)[tid];
    float4 bb = ((const float4*)bet)[tid];
    float o0 = dx * inv * gg.x + bb.x, o1 = dy * inv * gg.y + bb.y;
    float o2 = dz * inv * gg.z + bb.z, o3 = dw * inv * gg.w + bb.w;
    ushort4 st;
    st.x = f2bf(o0); st.y = f2bf(o1); st.z = f2bf(o2); st.w = f2bf(o3);
    ((ushort4*)(out + row * 1024))[tid] = st;
    float am = fmaxf(fmaxf(fabsf(o0), fabsf(o1)), fmaxf(fabsf(o2), fabsf(o3)));
#pragma unroll
    for (int o = 32; o > 0; o >>= 1) am = fmaxf(am, __shfl_xor(am, o));
    if ((tid & 63) == 0) atomicMax(scales + slot, __float_as_int(am));
}

// in-place elementwise qdq on a bf16 buffer (8 elems / thread)
__global__ void qact_k(u16* buf, int n8, const int* __restrict__ scales, int slot) {
    int i = blockIdx.x * 256 + threadIdx.x;
    if (i >= n8) return;
    const float s = getscale(scales, slot);
    uint4 u = ((const uint4*)buf)[i];
    unsigned w[4] = {u.x, u.y, u.z, u.w};
#pragma unroll
    for (int j = 0; j < 4; j++) {
        float lo = qdqv(bf2f((u16)(w[j] & 0xFFFFu)), s);
        float hi = qdqv(bf2f((u16)(w[j] >> 16)), s);
        w[j] = (unsigned)f2bf(lo) | ((unsigned)f2bf(hi) << 16);
    }
    uint4 o; o.x = w[0]; o.y = w[1]; o.z = w[2]; o.w = w[3];
    ((uint4*)buf)[i] = o;
}

// qdq + transpose V: v[B*H][S][32] bf16 -> vt[B*H][32][S] bf16
__global__ __launch_bounds__(256) void vtrans_k(const u16* __restrict__ v, u16* __restrict__ vt,
                                                const int* __restrict__ scales) {
    __shared__ u16 t[32][33];
    const int bh = blockIdx.y, s0 = blockIdx.x * 32;
    const float s = getscale(scales, 3);
    const int c = threadIdx.x & 31, r0 = threadIdx.x >> 5;
    const u16* src = v + ((long)bh * 1024 + s0) * 32;
#pragma unroll
    for (int i = 0; i < 4; i++) {
        int r = r0 + i * 8;
        t[r][c] = f2bf(qdqv(bf2f(src[r * 32 + c]), s));
    }
    __syncthreads();
    u16* dst = vt + (long)bh * 32768;
#pragma unroll
    for (int i = 0; i < 4; i++) {
        int r = r0 + i * 8;                       // d index
        dst[(long)r * 1024 + s0 + c] = t[c][r];
    }
}

// ---------------------------------------------------------------------------
// GEMM: C[M][N] = A[M][K](bf16, pre-qdq) * Bt[N][K](bf16, pre-qdq)^T + bias
// 128x128 tile, BK=32, 256 threads (4 waves in 2x2), m97-style staging.
// EPI 0: scatter to [B,H,S,HD] bf16 + absmax   (QKV)
// EPI 1: + resid -> fp32                       (Wo + residual)
// EPI 2: gelu(tanh) -> bf16 + absmax           (W1)
// EPI 3: -> fp32                               (W2, final out)
// ---------------------------------------------------------------------------
template <int EPI>
__global__ __launch_bounds__(256, 2) void gemm_k(const u16* __restrict__ A, const u16* __restrict__ Bt,
                                                 const float* __restrict__ bias, int M, int N, int K,
                                                 float* __restrict__ outf, u16* __restrict__ outb,
                                                 const float* __restrict__ resid,
                                                 int* __restrict__ scales, int slot) {
    __shared__ u16 As[128 * 32];
    __shared__ u16 Bs[128 * 32];
    const int tid = threadIdx.x;
    const int lane = tid & 63;
    const int wave = tid >> 6;
    const int wm = wave >> 1, wn = wave & 1;
    const int bm = blockIdx.y * 128, bn = blockIdx.x * 128;
    const int g = lane >> 4, c = lane & 15;

    const long astride = (long)K * 2;             // bytes per row
    const int srow = wave * 32 + (lane >> 2);     // staging row (+ i*16)
    const char* Ag = (const char*)A + (long)(bm + srow) * astride + (lane & 3) * 16;
    const char* Bg = (const char*)Bt + (long)(bn + srow) * astride + (lane & 3) * 16;
    char* Al = (char*)As + (wave * 32) * 64;      // wave-uniform LDS dest
    char* Bl = (char*)Bs + (wave * 32) * 64;

    f32x4 acc[4][4];
    const f32x4 zf = {0.f, 0.f, 0.f, 0.f};
#pragma unroll
    for (int i = 0; i < 4; i++)
#pragma unroll
        for (int j = 0; j < 4; j++) acc[i][j] = zf;

    const int nk = K >> 5;
    for (int kt = 0; kt < nk; ++kt) {
        __syncthreads();                          // protect LDS from prior reads
        const long ko = (long)kt * 64;
        gld16(Ag + ko, Al);
        gld16(Ag + ko + 16 * astride, Al + 1024);
        gld16(Bg + ko, Bl);
        gld16(Bg + ko + 16 * astride, Bl + 1024);
        __syncthreads();                          // vmcnt(0) drain before barrier

        bf16x8 af[4], bq[4];
#pragma unroll
        for (int i = 0; i < 4; i++)
            af[i] = *(const bf16x8*)((const char*)As + (wm * 64 + i * 16 + c) * 64 + g * 16);
#pragma unroll
        for (int j = 0; j < 4; j++)
            bq[j] = *(const bf16x8*)((const char*)Bs + (wn * 64 + j * 16 + c) * 64 + g * 16);
#pragma unroll
        for (int i = 0; i < 4; i++)
#pragma unroll
            for (int j = 0; j < 4; j++)
                acc[i][j] = MFMA(af[i], bq[j], acc[i][j]);
    }

    float am = 0.f;
#pragma unroll
    for (int i = 0; i < 4; i++) {
#pragma unroll
        for (int j = 0; j < 4; j++) {
#pragma unroll
            for (int t = 0; t < 4; t++) {
                const int row = bm + wm * 64 + i * 16 + g * 4 + t;
                const int col = bn + wn * 64 + j * 16 + c;
                float v = acc[i][j][t] + bias[col];
                if (EPI == 0) {
                    // [B*S][H*HD] -> [B,H,S,HD]
                    long oi = ((long)((row >> 10) * 32 + (col >> 5))) * 32768
                              + (long)(row & 1023) * 32 + (col & 31);
                    outb[oi] = f2bf(v);
                    am = fmaxf(am, fabsf(v));
                } else if (EPI == 1) {
                    long oi = (long)row * N + col;
                    outf[oi] = v + resid[oi];
                } else if (EPI == 2) {
                    float t3 = v * v * v;
                    float gl = 0.5f * v * (1.f + tanhf(0.79788456080286536f * (v + 0.044715f * t3)));
                    outb[(long)row * N + col] = f2bf(gl);
                    am = fmaxf(am, fabsf(gl));
                } else {
                    outf[(long)row * N + col] = v;
                }
            }
        }
    }
    if (EPI == 0 || EPI == 2) {
#pragma unroll
        for (int o = 32; o > 0; o >>= 1) am = fmaxf(am, __shfl_xor(am, o));
        if (lane == 0) atomicMax(scales + slot, __float_as_int(am));
    }
}

// ---------------------------------------------------------------------------
// Attention: per block = 1 wave, 32 q-rows of one (b,h). Flash-style online
// softmax over 32-key tiles. q,k pre-qdq'd [B*H][S][32]; vt pre-qdq'd
// [B*H][32][S]. scores = (qk + relpos[clip(qi-kj+32,0,64)][h]) / 32.
// ---------------------------------------------------------------------------
__global__ __launch_bounds__(64) void attn_k(const u16* __restrict__ q, const u16* __restrict__ k,
                                             const u16* __restrict__ vt, const float* __restrict__ relpos,
                                             u16* __restrict__ attn, int* __restrict__ scales) {
    __shared__ float rel[65];
    __shared__ u16 P[32 * 32];
    const int lane = threadIdx.x;
    const int bh = blockIdx.y;
    const int b = bh >> 5, h = bh & 31;
    const int q0 = blockIdx.x * 32;
    const int g = lane >> 4, c = lane & 15;
    for (int i = lane; i < 65; i += 64) rel[i] = relpos[i * 32 + h];
    __syncthreads();

    const u16* qb = q + ((long)bh * 1024 + q0) * 32;
    const u16* kb = k + (long)bh * 32768;
    const u16* vb = vt + (long)bh * 32768;

    bf16x8 aq[2];
#pragma unroll
    for (int i = 0; i < 2; i++) aq[i] = *(const bf16x8*)(qb + (i * 16 + c) * 32 + g * 8);

    const f32x4 zf = {0.f, 0.f, 0.f, 0.f};
    f32x4 o[2][2] = {{zf, zf}, {zf, zf}};
    float m_run[2][4], l_run[2][4];
#pragma unroll
    for (int i = 0; i < 2; i++)
#pragma unroll
        for (int t = 0; t < 4; t++) { m_run[i][t] = -1e30f; l_run[i][t] = 0.f; }

    for (int kt = 0; kt < 32; ++kt) {
        const int kk = kt * 32;
        bf16x8 bk0 = *(const bf16x8*)(kb + (long)(kk + c) * 32 + g * 8);
        bf16x8 bk1 = *(const bf16x8*)(kb + (long)(kk + 16 + c) * 32 + g * 8);
#pragma unroll
        for (int i = 0; i < 2; i++) {
            f32x4 s0 = MFMA(aq[i], bk0, zf);
            f32x4 s1 = MFMA(aq[i], bk1, zf);
#pragma unroll
            for (int t = 0; t < 4; t++) {
                const int qrow = q0 + i * 16 + g * 4 + t;
                int d0 = qrow - (kk + c) + 32;      d0 = min(max(d0, 0), 64);
                int d1 = qrow - (kk + 16 + c) + 32; d1 = min(max(d1, 0), 64);
                float v0 = (s0[t] + rel[d0]) * 0.03125f;
                float v1 = (s1[t] + rel[d1]) * 0.03125f;
                float mt = fmaxf(v0, v1);
                mt = fmaxf(mt, __shfl_xor(mt, 1));
                mt = fmaxf(mt, __shfl_xor(mt, 2));
                mt = fmaxf(mt, __shfl_xor(mt, 4));
                mt = fmaxf(mt, __shfl_xor(mt, 8));
                const float mo = m_run[i][t];
                const float mn = fmaxf(mo, mt);
                const float fr = expf(mo - mn);
                const float p0 = expf(v0 - mn), p1 = expf(v1 - mn);
                float sm = p0 + p1;
                sm += __shfl_xor(sm, 1);
                sm += __shfl_xor(sm, 2);
                sm += __shfl_xor(sm, 4);
                sm += __shfl_xor(sm, 8);
                l_run[i][t] = l_run[i][t] * fr + sm;
                m_run[i][t] = mn;
                o[i][0][t] *= fr;
                o[i][1][t] *= fr;
                const int pr = (i * 16 + g * 4 + t) * 32;
                P[pr + c] = f2bf(p0);
                P[pr + c + 16] = f2bf(p1);
            }
        }
        __syncthreads();
        bf16x8 bv0 = *(const bf16x8*)(vb + (long)c * 1024 + kk + g * 8);
        bf16x8 bv1 = *(const bf16x8*)(vb + (long)(16 + c) * 1024 + kk + g * 8);
#pragma unroll
        for (int i = 0; i < 2; i++) {
            bf16x8 ap = *(const bf16x8*)(P + (i * 16 + c) * 32 + g * 8);
            o[i][0] = MFMA(ap, bv0, o[i][0]);
            o[i][1] = MFMA(ap, bv1, o[i][1]);
        }
        __syncthreads();
    }

    float am = 0.f;
#pragma unroll
    for (int i = 0; i < 2; i++)
#pragma unroll
        for (int j = 0; j < 2; j++)
#pragma unroll
            for (int t = 0; t < 4; t++) {
                float val = o[i][j][t] / (l_run[i][t] + 1e-6f);
                long row = (long)b * 1024 + q0 + i * 16 + g * 4 + t;
                attn[row * 1024 + h * 32 + j * 16 + c] = f2bf(val);
                am = fmaxf(am, fabsf(val));
            }
#pragma unroll
    for (int o2 = 32; o2 > 0; o2 >>= 1) am = fmaxf(am, __shfl_xor(am, o2));
    if (lane == 0) atomicMax(scales + 4, __float_as_int(am));
}

// ---------------------------------------------------------------------------
extern "C" void kernel_launch(void* const* d_in, const int* in_sizes, int n_in,
                              void* d_out, int out_size, void* d_ws, size_t ws_size,
                              hipStream_t stream) {
    (void)in_sizes; (void)n_in; (void)out_size; (void)ws_size;
    const float* inputs = (const float*)d_in[0];
    const float* ln1s   = (const float*)d_in[1];
    const float* ln1b   = (const float*)d_in[2];
    const float* Wq     = (const float*)d_in[3];
    const float* bq     = (const float*)d_in[4];
    const float* Wk     = (const float*)d_in[5];
    const float* bk     = (const float*)d_in[6];
    const float* Wv     = (const float*)d_in[7];
    const float* bv     = (const float*)d_in[8];
    const float* rel    = (const float*)d_in[9];
    const float* Wo     = (const float*)d_in[10];
    const float* bo     = (const float*)d_in[11];
    const float* ln2s   = (const float*)d_in[12];
    const float* ln2b   = (const float*)d_in[13];
    const float* W1     = (const float*)d_in[14];
    const float* b1     = (const float*)d_in[15];
    const float* W2     = (const float*)d_in[16];
    const float* b2     = (const float*)d_in[17];
    float* out = (float*)d_out;

    // workspace layout (88 MB + 4 KB), with aliasing:
    //   [scales 4KB][q 8M][k 8M][v 8M][vt 8M][xq/attn 8M][xr 16M][y 8M][Wt 24M]
    //   h (32MB) aliases q..vt after attention+Wo are done.
    char* ws = (char*)d_ws;
    int* scales = (int*)ws;
    u16* qb   = (u16*)(ws + 4096);
    u16* kbuf = qb + 4194304;
    u16* vbuf = kbuf + 4194304;
    u16* vtb  = vbuf + 4194304;
    u16* hb   = qb;                       // alias (32MB region)
    u16* xq   = vtb + 4194304;
    u16* attnb = xq;                      // alias (xq dead after QKV gemms)
    float* xr = (float*)(xq + 4194304);
    u16* yb   = (u16*)(xr + 4194304);
    u16* wtq  = yb + 4194304;
    u16* wtk  = wtq + 1048576;
    u16* wtv  = wtk + 1048576;
    u16* wto  = wtv + 1048576;
    u16* wt1  = wto + 1048576;
    u16* wt2  = wt1 + 4194304;

    // slots: 0=x 1=q 2=k 3=v 4=attn 5=y 6=h 7..12=Wq,Wk,Wv,Wo,W1,W2
    zero_k<<<1, 64, 0, stream>>>(scales);
    wabsmax_k<<<256, 256, 0, stream>>>(Wq, 1048576, scales, 7);
    wabsmax_k<<<256, 256, 0, stream>>>(Wk, 1048576, scales, 8);
    wabsmax_k<<<256, 256, 0, stream>>>(Wv, 1048576, scales, 9);
    wabsmax_k<<<256, 256, 0, stream>>>(Wo, 1048576, scales, 10);
    wabsmax_k<<<512, 256, 0, stream>>>(W1, 4194304, scales, 11);
    wabsmax_k<<<512, 256, 0, stream>>>(W2, 4194304, scales, 12);

    ln_k<<<4096, 256, 0, stream>>>(inputs, ln1s, ln1b, xq, scales, 0);

    wqt_k<<<dim3(32, 32), 256, 0, stream>>>(Wq, wtq, 1024, 1024, scales, 7);
    wqt_k<<<dim3(32, 32), 256, 0, stream>>>(Wk, wtk, 1024, 1024, scales, 8);
    wqt_k<<<dim3(32, 32), 256, 0, stream>>>(Wv, wtv, 1024, 1024, scales, 9);
    wqt_k<<<dim3(32, 32), 256, 0, stream>>>(Wo, wto, 1024, 1024, scales, 10);
    wqt_k<<<dim3(128, 32), 256, 0, stream>>>(W1, wt1, 1024, 4096, scales, 11);
    wqt_k<<<dim3(32, 128), 256, 0, stream>>>(W2, wt2, 4096, 1024, scales, 12);

    qact_k<<<2048, 256, 0, stream>>>(xq, 524288, scales, 0);

    gemm_k<0><<<dim3(8, 32), 256, 0, stream>>>(xq, wtq, bq, 4096, 1024, 1024, nullptr, qb,   nullptr, scales, 1);
    gemm_k<0><<<dim3(8, 32), 256, 0, stream>>>(xq, wtk, bk, 4096, 1024, 1024, nullptr, kbuf, nullptr, scales, 2);
    gemm_k<0><<<dim3(8, 32), 256, 0, stream>>>(xq, wtv, bv, 4096, 1024, 1024, nullptr, vbuf, nullptr, scales, 3);

    qact_k<<<2048, 256, 0, stream>>>(qb, 524288, scales, 1);
    qact_k<<<2048, 256, 0, stream>>>(kbuf, 524288, scales, 2);
    vtrans_k<<<dim3(32, 128), 256, 0, stream>>>(vbuf, vtb, scales);

    attn_k<<<dim3(32, 128), 64, 0, stream>>>(qb, kbuf, vtb, rel, attnb, scales);
    qact_k<<<2048, 256, 0, stream>>>(attnb, 524288, scales, 4);

    gemm_k<1><<<dim3(8, 32), 256, 0, stream>>>(attnb, wto, bo, 4096, 1024, 1024, xr, nullptr, inputs, scales, -1);

    ln_k<<<4096, 256, 0, stream>>>(xr, ln2s, ln2b, yb, scales, 5);
    qact_k<<<2048, 256, 0, stream>>>(yb, 524288, scales, 5);

    gemm_k<2><<<dim3(32, 32), 256, 0, stream>>>(yb, wt1, b1, 4096, 4096, 1024, nullptr, hb, nullptr, scales, 6);
    qact_k<<<8192, 256, 0, stream>>>(hb, 2097152, scales, 6);

    gemm_k<3><<<dim3(8, 32), 256, 0, stream>>>(hb, wt2, b2, 4096, 1024, 4096, out, nullptr, nullptr, scales, -1);
}

// Round 2
// 730.892 us; speedup vs baseline: 1.4481x; 1.4481x over previous
//
#include <hip/hip_runtime.h>
#include <cstdint>

// ---------------------------------------------------------------------------
// TransformerBlock: LN1 -> qdq -> QKV gemms -> attn(relpos bias) -> Wo gemm
//  -> +resid -> LN2 -> W1 gemm -> gelu(tanh) -> W2 gemm.
// Per-tensor int8 QDQ on every GEMM input (activations and weights).
// bf16 MFMA (16x16x32) for all GEMMs; fp32 for LN/softmax/residual/absmax.
// R1: hierarchical absmax (64 partial slots/scale, spread atomics) -- kills
//     the 16K same-address atomicMax serialization that made ln_k 190us.
// ---------------------------------------------------------------------------

typedef unsigned short u16;
typedef __bf16 bf16x8 __attribute__((ext_vector_type(8)));
typedef float  f32x4  __attribute__((ext_vector_type(4)));

#define MFMA(a, b, c) __builtin_amdgcn_mfma_f32_16x16x32_bf16(a, b, c, 0, 0, 0)

#define NSLOT 13
#define PSPREAD 64   // partial slots per logical scale

__device__ __forceinline__ float bf2f(u16 h) {
    return __uint_as_float(((unsigned)h) << 16);
}
__device__ __forceinline__ u16 f2bf(float f) {   // RNE
    unsigned u = __float_as_uint(f);
    u += 0x7FFFu + ((u >> 16) & 1u);
    return (u16)(u >> 16);
}
__device__ __forceinline__ float qdqv(float v, float s) {
    float q = rintf(v / s);                       // rint = RNE, matches jnp.round
    q = fminf(fmaxf(q, -127.f), 127.f);
    return q * s;
}

// wave-cooperative: reduce the 64 partial absmax ints of `slot` -> scale.
// All lanes of every wave must call (uniform). 1 load + 6 shuffles.
__device__ __forceinline__ float getscale64(const int* scales, int slot) {
    float m = __int_as_float(scales[slot * PSPREAD + (threadIdx.x & 63)]);
#pragma unroll
    for (int o = 32; o > 0; o >>= 1) m = fmaxf(m, __shfl_xor(m, o));
    return fmaxf(m / 127.f, 1e-8f);
}

// global -> LDS direct (16B per lane; LDS dest is wave-uniform base + lane*16)
typedef const __attribute__((address_space(1))) unsigned gas_u32;
typedef __attribute__((address_space(3))) unsigned las_u32;
__device__ __forceinline__ void gld16(const void* g, void* l) {
    __builtin_amdgcn_global_load_lds((gas_u32*)g, (las_u32*)l, 16, 0, 0);
}

// ---------------------------------------------------------------------------
__global__ void zero_k(int* s) {
    if (threadIdx.x < NSLOT * PSPREAD) s[threadIdx.x] = 0;
}

// grid-stride absmax of an fp32 tensor -> spread partial slots
__global__ void wabsmax_k(const float* __restrict__ w, int n, int* scales, int slot) {
    float m = 0.f;
    for (int i = blockIdx.x * blockDim.x + threadIdx.x; i < n; i += gridDim.x * blockDim.x)
        m = fmaxf(m, fabsf(w[i]));
#pragma unroll
    for (int o = 32; o > 0; o >>= 1) m = fmaxf(m, __shfl_xor(m, o));
    if ((threadIdx.x & 63) == 0)
        atomicMax(scales + slot * PSPREAD + ((blockIdx.x * 4 + (threadIdx.x >> 6)) & (PSPREAD - 1)),
                  __float_as_int(m));
}

// quantize (qdq) + transpose weight: W[K][N] fp32 -> Wt[N][K] bf16
__global__ __launch_bounds__(256) void wqt_k(const float* __restrict__ W, u16* __restrict__ Wt,
                                             int K, int N, const int* __restrict__ scales, int slot) {
    __shared__ float t[32][33];
    const int n0 = blockIdx.x * 32, k0 = blockIdx.y * 32;
    const float s = getscale64(scales, slot);
    const int c = threadIdx.x & 31, r0 = threadIdx.x >> 5;   // 8 rows per pass
#pragma unroll
    for (int i = 0; i < 4; i++) {
        int kk = k0 + r0 + i * 8;
        t[r0 + i * 8][c] = qdqv(W[(long)kk * N + n0 + c], s);
    }
    __syncthreads();
#pragma unroll
    for (int i = 0; i < 4; i++) {
        int nn = n0 + r0 + i * 8;
        Wt[(long)nn * K + k0 + c] = f2bf(t[c][r0 + i * 8]);
    }
}

// block reduction helper (256 threads, 4 waves)
__device__ __forceinline__ float blk_sum(float v, float* red) {
#pragma unroll
    for (int o = 32; o > 0; o >>= 1) v += __shfl_xor(v, o);
    __syncthreads();
    if ((threadIdx.x & 63) == 0) red[threadIdx.x >> 6] = v;
    __syncthreads();
    return red[0] + red[1] + red[2] + red[3];
}

// LayerNorm (eps=1e-6): fp32 in -> bf16 out (raw, pre-qdq), absmax -> slot
__global__ __launch_bounds__(256) void ln_k(const float* __restrict__ in, const float* __restrict__ gam,
                                            const float* __restrict__ bet, u16* __restrict__ out,
                                            int* __restrict__ scales, int slot) {
    __shared__ float red[4];
    const long row = blockIdx.x;
    const int tid = threadIdx.x;
    float4 v = ((const float4*)(in + row * 1024))[tid];
    float mean = blk_sum(v.x + v.y + v.z + v.w, red) * (1.f / 1024.f);
    float dx = v.x - mean, dy = v.y - mean, dz = v.z - mean, dw = v.w - mean;
    float var = blk_sum(dx * dx + dy * dy + dz * dz + dw * dw, red) * (1.f / 1024.f);
    float inv = rsqrtf(var + 1e-6f);
    float4 gg = ((const float4*)gam)[tid];
    float4 bb = ((const float4*)bet)[tid];
    float o0 = dx * inv * gg.x + bb.x, o1 = dy * inv * gg.y + bb.y;
    float o2 = dz * inv * gg.z + bb.z, o3 = dw * inv * gg.w + bb.w;
    ushort4 st;
    st.x = f2bf(o0); st.y = f2bf(o1); st.z = f2bf(o2); st.w = f2bf(o3);
    ((ushort4*)(out + row * 1024))[tid] = st;
    float am = fmaxf(fmaxf(fabsf(o0), fabsf(o1)), fmaxf(fabsf(o2), fabsf(o3)));
#pragma unroll
    for (int o = 32; o > 0; o >>= 1) am = fmaxf(am, __shfl_xor(am, o));
    if ((tid & 63) == 0)
        atomicMax(scales + slot * PSPREAD + ((blockIdx.x * 4 + (tid >> 6)) & (PSPREAD - 1)),
                  __float_as_int(am));
}

// in-place elementwise qdq on a bf16 buffer (8 elems / thread)
__global__ void qact_k(u16* buf, int n8, const int* __restrict__ scales, int slot) {
    const float s = getscale64(scales, slot);     // uniform, before any early-out
    int i = blockIdx.x * 256 + threadIdx.x;
    if (i >= n8) return;
    uint4 u = ((const uint4*)buf)[i];
    unsigned w[4] = {u.x, u.y, u.z, u.w};
#pragma unroll
    for (int j = 0; j < 4; j++) {
        float lo = qdqv(bf2f((u16)(w[j] & 0xFFFFu)), s);
        float hi = qdqv(bf2f((u16)(w[j] >> 16)), s);
        w[j] = (unsigned)f2bf(lo) | ((unsigned)f2bf(hi) << 16);
    }
    uint4 o; o.x = w[0]; o.y = w[1]; o.z = w[2]; o.w = w[3];
    ((uint4*)buf)[i] = o;
}

// qdq + transpose V: v[B*H][S][32] bf16 -> vt[B*H][32][S] bf16
__global__ __launch_bounds__(256) void vtrans_k(const u16* __restrict__ v, u16* __restrict__ vt,
                                                const int* __restrict__ scales) {
    __shared__ u16 t[32][33];
    const int bh = blockIdx.y, s0 = blockIdx.x * 32;
    const float s = getscale64(scales, 3);
    const int c = threadIdx.x & 31, r0 = threadIdx.x >> 5;
    const u16* src = v + ((long)bh * 1024 + s0) * 32;
#pragma unroll
    for (int i = 0; i < 4; i++) {
        int r = r0 + i * 8;
        t[r][c] = f2bf(qdqv(bf2f(src[r * 32 + c]), s));
    }
    __syncthreads();
    u16* dst = vt + (long)bh * 32768;
#pragma unroll
    for (int i = 0; i < 4; i++) {
        int r = r0 + i * 8;                       // d index
        dst[(long)r * 1024 + s0 + c] = t[c][r];
    }
}

// ---------------------------------------------------------------------------
// GEMM: C[M][N] = A[M][K](bf16, pre-qdq) * Bt[N][K](bf16, pre-qdq)^T + bias
// 128x128 tile, BK=32, 256 threads (4 waves in 2x2), m97-style staging.
// EPI 0: scatter to [B,H,S,HD] bf16 + absmax   (QKV)
// EPI 1: + resid -> fp32                       (Wo + residual)
// EPI 2: gelu(tanh) -> bf16 + absmax           (W1)
// EPI 3: -> fp32                               (W2, final out)
// ---------------------------------------------------------------------------
template <int EPI>
__global__ __launch_bounds__(256, 2) void gemm_k(const u16* __restrict__ A, const u16* __restrict__ Bt,
                                                 const float* __restrict__ bias, int M, int N, int K,
                                                 float* __restrict__ outf, u16* __restrict__ outb,
                                                 const float* __restrict__ resid,
                                                 int* __restrict__ scales, int slot) {
    __shared__ u16 As[128 * 32];
    __shared__ u16 Bs[128 * 32];
    const int tid = threadIdx.x;
    const int lane = tid & 63;
    const int wave = tid >> 6;
    const int wm = wave >> 1, wn = wave & 1;
    const int bm = blockIdx.y * 128, bn = blockIdx.x * 128;
    const int g = lane >> 4, c = lane & 15;

    const long astride = (long)K * 2;             // bytes per row
    const int srow = wave * 32 + (lane >> 2);     // staging row (+ i*16)
    const char* Ag = (const char*)A + (long)(bm + srow) * astride + (lane & 3) * 16;
    const char* Bg = (const char*)Bt + (long)(bn + srow) * astride + (lane & 3) * 16;
    char* Al = (char*)As + (wave * 32) * 64;      // wave-uniform LDS dest
    char* Bl = (char*)Bs + (wave * 32) * 64;

    f32x4 acc[4][4];
    const f32x4 zf = {0.f, 0.f, 0.f, 0.f};
#pragma unroll
    for (int i = 0; i < 4; i++)
#pragma unroll
        for (int j = 0; j < 4; j++) acc[i][j] = zf;

    const int nk = K >> 5;
    for (int kt = 0; kt < nk; ++kt) {
        __syncthreads();                          // protect LDS from prior reads
        const long ko = (long)kt * 64;
        gld16(Ag + ko, Al);
        gld16(Ag + ko + 16 * astride, Al + 1024);
        gld16(Bg + ko, Bl);
        gld16(Bg + ko + 16 * astride, Bl + 1024);
        __syncthreads();                          // vmcnt(0) drain before barrier

        bf16x8 af[4], bq[4];
#pragma unroll
        for (int i = 0; i < 4; i++)
            af[i] = *(const bf16x8*)((const char*)As + (wm * 64 + i * 16 + c) * 64 + g * 16);
#pragma unroll
        for (int j = 0; j < 4; j++)
            bq[j] = *(const bf16x8*)((const char*)Bs + (wn * 64 + j * 16 + c) * 64 + g * 16);
#pragma unroll
        for (int i = 0; i < 4; i++)
#pragma unroll
            for (int j = 0; j < 4; j++)
                acc[i][j] = MFMA(af[i], bq[j], acc[i][j]);
    }

    float am = 0.f;
#pragma unroll
    for (int i = 0; i < 4; i++) {
#pragma unroll
        for (int j = 0; j < 4; j++) {
#pragma unroll
            for (int t = 0; t < 4; t++) {
                const int row = bm + wm * 64 + i * 16 + g * 4 + t;
                const int col = bn + wn * 64 + j * 16 + c;
                float v = acc[i][j][t] + bias[col];
                if (EPI == 0) {
                    // [B*S][H*HD] -> [B,H,S,HD]
                    long oi = ((long)((row >> 10) * 32 + (col >> 5))) * 32768
                              + (long)(row & 1023) * 32 + (col & 31);
                    outb[oi] = f2bf(v);
                    am = fmaxf(am, fabsf(v));
                } else if (EPI == 1) {
                    long oi = (long)row * N + col;
                    outf[oi] = v + resid[oi];
                } else if (EPI == 2) {
                    float t3 = v * v * v;
                    float gl = 0.5f * v * (1.f + tanhf(0.79788456080286536f * (v + 0.044715f * t3)));
                    outb[(long)row * N + col] = f2bf(gl);
                    am = fmaxf(am, fabsf(gl));
                } else {
                    outf[(long)row * N + col] = v;
                }
            }
        }
    }
    if (EPI == 0 || EPI == 2) {
#pragma unroll
        for (int o = 32; o > 0; o >>= 1) am = fmaxf(am, __shfl_xor(am, o));
        if (lane == 0)
            atomicMax(scales + slot * PSPREAD
                          + (((blockIdx.x + blockIdx.y * gridDim.x) * 4 + wave) & (PSPREAD - 1)),
                      __float_as_int(am));
    }
}

// ---------------------------------------------------------------------------
// Attention: per block = 1 wave, 32 q-rows of one (b,h). Flash-style online
// softmax over 32-key tiles. q,k pre-qdq'd [B*H][S][32]; vt pre-qdq'd
// [B*H][32][S]. scores = (qk + relpos[clip(qi-kj+32,0,64)][h]) / 32.
// ---------------------------------------------------------------------------
__global__ __launch_bounds__(64) void attn_k(const u16* __restrict__ q, const u16* __restrict__ k,
                                             const u16* __restrict__ vt, const float* __restrict__ relpos,
                                             u16* __restrict__ attn, int* __restrict__ scales) {
    __shared__ float rel[65];
    __shared__ u16 P[32 * 32];
    const int lane = threadIdx.x;
    const int bh = blockIdx.y;
    const int b = bh >> 5, h = bh & 31;
    const int q0 = blockIdx.x * 32;
    const int g = lane >> 4, c = lane & 15;
    for (int i = lane; i < 65; i += 64) rel[i] = relpos[i * 32 + h];
    __syncthreads();

    const u16* qb = q + ((long)bh * 1024 + q0) * 32;
    const u16* kb = k + (long)bh * 32768;
    const u16* vb = vt + (long)bh * 32768;

    bf16x8 aq[2];
#pragma unroll
    for (int i = 0; i < 2; i++) aq[i] = *(const bf16x8*)(qb + (i * 16 + c) * 32 + g * 8);

    const f32x4 zf = {0.f, 0.f, 0.f, 0.f};
    f32x4 o[2][2] = {{zf, zf}, {zf, zf}};
    float m_run[2][4], l_run[2][4];
#pragma unroll
    for (int i = 0; i < 2; i++)
#pragma unroll
        for (int t = 0; t < 4; t++) { m_run[i][t] = -1e30f; l_run[i][t] = 0.f; }

    for (int kt = 0; kt < 32; ++kt) {
        const int kk = kt * 32;
        bf16x8 bk0 = *(const bf16x8*)(kb + (long)(kk + c) * 32 + g * 8);
        bf16x8 bk1 = *(const bf16x8*)(kb + (long)(kk + 16 + c) * 32 + g * 8);
#pragma unroll
        for (int i = 0; i < 2; i++) {
            f32x4 s0 = MFMA(aq[i], bk0, zf);
            f32x4 s1 = MFMA(aq[i], bk1, zf);
#pragma unroll
            for (int t = 0; t < 4; t++) {
                const int qrow = q0 + i * 16 + g * 4 + t;
                int d0 = qrow - (kk + c) + 32;      d0 = min(max(d0, 0), 64);
                int d1 = qrow - (kk + 16 + c) + 32; d1 = min(max(d1, 0), 64);
                float v0 = (s0[t] + rel[d0]) * 0.03125f;
                float v1 = (s1[t] + rel[d1]) * 0.03125f;
                float mt = fmaxf(v0, v1);
                mt = fmaxf(mt, __shfl_xor(mt, 1));
                mt = fmaxf(mt, __shfl_xor(mt, 2));
                mt = fmaxf(mt, __shfl_xor(mt, 4));
                mt = fmaxf(mt, __shfl_xor(mt, 8));
                const float mo = m_run[i][t];
                const float mn = fmaxf(mo, mt);
                const float fr = expf(mo - mn);
                const float p0 = expf(v0 - mn), p1 = expf(v1 - mn);
                float sm = p0 + p1;
                sm += __shfl_xor(sm, 1);
                sm += __shfl_xor(sm, 2);
                sm += __shfl_xor(sm, 4);
                sm += __shfl_xor(sm, 8);
                l_run[i][t] = l_run[i][t] * fr + sm;
                m_run[i][t] = mn;
                o[i][0][t] *= fr;
                o[i][1][t] *= fr;
                const int pr = (i * 16 + g * 4 + t) * 32;
                P[pr + c] = f2bf(p0);
                P[pr + c + 16] = f2bf(p1);
            }
        }
        __syncthreads();
        bf16x8 bv0 = *(const bf16x8*)(vb + (long)c * 1024 + kk + g * 8);
        bf16x8 bv1 = *(const bf16x8*)(vb + (long)(16 + c) * 1024 + kk + g * 8);
#pragma unroll
        for (int i = 0; i < 2; i++) {
            bf16x8 ap = *(const bf16x8*)(P + (i * 16 + c) * 32 + g * 8);
            o[i][0] = MFMA(ap, bv0, o[i][0]);
            o[i][1] = MFMA(ap, bv1, o[i][1]);
        }
        __syncthreads();
    }

    float am = 0.f;
#pragma unroll
    for (int i = 0; i < 2; i++)
#pragma unroll
        for (int j = 0; j < 2; j++)
#pragma unroll
            for (int t = 0; t < 4; t++) {
                float val = o[i][j][t] / (l_run[i][t] + 1e-6f);
                long row = (long)b * 1024 + q0 + i * 16 + g * 4 + t;
                attn[row * 1024 + h * 32 + j * 16 + c] = f2bf(val);
                am = fmaxf(am, fabsf(val));
            }
#pragma unroll
    for (int o2 = 32; o2 > 0; o2 >>= 1) am = fmaxf(am, __shfl_xor(am, o2));
    if (lane == 0)
        atomicMax(scales + 4 * PSPREAD + ((blockIdx.x + blockIdx.y * 32) & (PSPREAD - 1)),
                  __float_as_int(am));
}

// ---------------------------------------------------------------------------
extern "C" void kernel_launch(void* const* d_in, const int* in_sizes, int n_in,
                              void* d_out, int out_size, void* d_ws, size_t ws_size,
                              hipStream_t stream) {
    (void)in_sizes; (void)n_in; (void)out_size; (void)ws_size;
    const float* inputs = (const float*)d_in[0];
    const float* ln1s   = (const float*)d_in[1];
    const float* ln1b   = (const float*)d_in[2];
    const float* Wq     = (const float*)d_in[3];
    const float* bq     = (const float*)d_in[4];
    const float* Wk     = (const float*)d_in[5];
    const float* bk     = (const float*)d_in[6];
    const float* Wv     = (const float*)d_in[7];
    const float* bv     = (const float*)d_in[8];
    const float* rel    = (const float*)d_in[9];
    const float* Wo     = (const float*)d_in[10];
    const float* bo     = (const float*)d_in[11];
    const float* ln2s   = (const float*)d_in[12];
    const float* ln2b   = (const float*)d_in[13];
    const float* W1     = (const float*)d_in[14];
    const float* b1     = (const float*)d_in[15];
    const float* W2     = (const float*)d_in[16];
    const float* b2     = (const float*)d_in[17];
    float* out = (float*)d_out;

    // workspace layout (88 MB + 4 KB), with aliasing:
    //   [scales 4KB][q 8M][k 8M][v 8M][vt 8M][xq/attn 8M][xr 16M][y 8M][Wt 24M]
    //   h (32MB) aliases q..vt after attention+Wo are done.
    char* ws = (char*)d_ws;
    int* scales = (int*)ws;
    u16* qb   = (u16*)(ws + 4096);
    u16* kbuf = qb + 4194304;
    u16* vbuf = kbuf + 4194304;
    u16* vtb  = vbuf + 4194304;
    u16* hb   = qb;                       // alias (32MB region)
    u16* xq   = vtb + 4194304;
    u16* attnb = xq;                      // alias (xq dead after QKV gemms)
    float* xr = (float*)(xq + 4194304);
    u16* yb   = (u16*)(xr + 4194304);
    u16* wtq  = yb + 4194304;
    u16* wtk  = wtq + 1048576;
    u16* wtv  = wtk + 1048576;
    u16* wto  = wtv + 1048576;
    u16* wt1  = wto + 1048576;
    u16* wt2  = wt1 + 4194304;

    // slots: 0=x 1=q 2=k 3=v 4=attn 5=y 6=h 7..12=Wq,Wk,Wv,Wo,W1,W2
    zero_k<<<1, 1024, 0, stream>>>(scales);
    wabsmax_k<<<256, 256, 0, stream>>>(Wq, 1048576, scales, 7);
    wabsmax_k<<<256, 256, 0, stream>>>(Wk, 1048576, scales, 8);
    wabsmax_k<<<256, 256, 0, stream>>>(Wv, 1048576, scales, 9);
    wabsmax_k<<<256, 256, 0, stream>>>(Wo, 1048576, scales, 10);
    wabsmax_k<<<512, 256, 0, stream>>>(W1, 4194304, scales, 11);
    wabsmax_k<<<512, 256, 0, stream>>>(W2, 4194304, scales, 12);

    ln_k<<<4096, 256, 0, stream>>>(inputs, ln1s, ln1b, xq, scales, 0);

    wqt_k<<<dim3(32, 32), 256, 0, stream>>>(Wq, wtq, 1024, 1024, scales, 7);
    wqt_k<<<dim3(32, 32), 256, 0, stream>>>(Wk, wtk, 1024, 1024, scales, 8);
    wqt_k<<<dim3(32, 32), 256, 0, stream>>>(Wv, wtv, 1024, 1024, scales, 9);
    wqt_k<<<dim3(32, 32), 256, 0, stream>>>(Wo, wto, 1024, 1024, scales, 10);
    wqt_k<<<dim3(128, 32), 256, 0, stream>>>(W1, wt1, 1024, 4096, scales, 11);
    wqt_k<<<dim3(32, 128), 256, 0, stream>>>(W2, wt2, 4096, 1024, scales, 12);

    qact_k<<<2048, 256, 0, stream>>>(xq, 524288, scales, 0);

    gemm_k<0><<<dim3(8, 32), 256, 0, stream>>>(xq, wtq, bq, 4096, 1024, 1024, nullptr, qb,   nullptr, scales, 1);
    gemm_k<0><<<dim3(8, 32), 256, 0, stream>>>(xq, wtk, bk, 4096, 1024, 1024, nullptr, kbuf, nullptr, scales, 2);
    gemm_k<0><<<dim3(8, 32), 256, 0, stream>>>(xq, wtv, bv, 4096, 1024, 1024, nullptr, vbuf, nullptr, scales, 3);

    qact_k<<<2048, 256, 0, stream>>>(qb, 524288, scales, 1);
    qact_k<<<2048, 256, 0, stream>>>(kbuf, 524288, scales, 2);
    vtrans_k<<<dim3(32, 128), 256, 0, stream>>>(vbuf, vtb, scales);

    attn_k<<<dim3(32, 128), 64, 0, stream>>>(qb, kbuf, vtb, rel, attnb, scales);
    qact_k<<<2048, 256, 0, stream>>>(attnb, 524288, scales, 4);

    gemm_k<1><<<dim3(8, 32), 256, 0, stream>>>(attnb, wto, bo, 4096, 1024, 1024, xr, nullptr, inputs, scales, -1);

    ln_k<<<4096, 256, 0, stream>>>(xr, ln2s, ln2b, yb, scales, 5);
    qact_k<<<2048, 256, 0, stream>>>(yb, 524288, scales, 5);

    gemm_k<2><<<dim3(32, 32), 256, 0, stream>>>(yb, wt1, b1, 4096, 4096, 1024, nullptr, hb, nullptr, scales, 6);
    qact_k<<<8192, 256, 0, stream>>>(hb, 2097152, scales, 6);

    gemm_k<3><<<dim3(8, 32), 256, 0, stream>>>(hb, wt2, b2, 4096, 1024, 4096, out, nullptr, nullptr, scales, -1);
}

// Round 3
// 548.800 us; speedup vs baseline: 1.9286x; 1.3318x over previous
//
#include <hip/hip_runtime.h>
#include <cstdint>

// ---------------------------------------------------------------------------
// TransformerBlock: LN1 -> qdq -> QKV gemms -> attn(relpos bias) -> Wo gemm
//  -> +resid -> LN2 -> W1 gemm -> gelu(tanh) -> W2 gemm.
// R1: hierarchical absmax (64 partial slots/scale, spread atomics).
// R2: attn_k rewritten with swapped QK^T (lane-local softmax, 2 shuffles per
//     reduce instead of 64), uniform-rel-bias fast path for the 29/32 k-tiles
//     away from the diagonal, padded P tile; fused wabsmax6; fused QKV gemm.
// ---------------------------------------------------------------------------

typedef unsigned short u16;
typedef __bf16 bf16x4 __attribute__((ext_vector_type(4)));
typedef __bf16 bf16x8 __attribute__((ext_vector_type(8)));
typedef float  f32x4  __attribute__((ext_vector_type(4)));

#define MFMA(a, b, c) __builtin_amdgcn_mfma_f32_16x16x32_bf16(a, b, c, 0, 0, 0)

#define NSLOT 13
#define PSPREAD 64   // partial slots per logical scale

__device__ __forceinline__ float bf2f(u16 h) {
    return __uint_as_float(((unsigned)h) << 16);
}
__device__ __forceinline__ u16 f2bf(float f) {   // RNE
    unsigned u = __float_as_uint(f);
    u += 0x7FFFu + ((u >> 16) & 1u);
    return (u16)(u >> 16);
}
__device__ __forceinline__ float qdqv(float v, float s) {
    float q = rintf(v / s);                       // rint = RNE, matches jnp.round
    q = fminf(fmaxf(q, -127.f), 127.f);
    return q * s;
}

// wave-cooperative: reduce the 64 partial absmax ints of `slot` -> scale.
__device__ __forceinline__ float getscale64(const int* scales, int slot) {
    float m = __int_as_float(scales[slot * PSPREAD + (threadIdx.x & 63)]);
#pragma unroll
    for (int o = 32; o > 0; o >>= 1) m = fmaxf(m, __shfl_xor(m, o));
    return fmaxf(m / 127.f, 1e-8f);
}

// global -> LDS direct (16B per lane; LDS dest is wave-uniform base + lane*16)
typedef const __attribute__((address_space(1))) unsigned gas_u32;
typedef __attribute__((address_space(3))) unsigned las_u32;
__device__ __forceinline__ void gld16(const void* g, void* l) {
    __builtin_amdgcn_global_load_lds((gas_u32*)g, (las_u32*)l, 16, 0, 0);
}

// ---------------------------------------------------------------------------
__global__ void zero_k(int* s) {
    if (threadIdx.x < NSLOT * PSPREAD) s[threadIdx.x] = 0;
}

// fused absmax of the six weight tensors -> slots 7..12 (one launch).
// w0..w3: 1M floats (slots 7..10); w4,w5: 4M floats (slots 11,12).
// grid 3072 x 256: each block covers 4096 consecutive floats of one tensor.
__global__ __launch_bounds__(256) void wabsmax6_k(const float* __restrict__ w0, const float* __restrict__ w1,
                                                  const float* __restrict__ w2, const float* __restrict__ w3,
                                                  const float* __restrict__ w4, const float* __restrict__ w5,
                                                  int* scales) {
    const int b = blockIdx.x;
    int ti, boff;
    if (b < 1024)      { ti = b >> 8; boff = (b & 255) * 4096; }
    else if (b < 2048) { ti = 4;      boff = (b - 1024) * 4096; }
    else               { ti = 5;      boff = (b - 2048) * 4096; }
    const float* w = (ti == 0) ? w0 : (ti == 1) ? w1 : (ti == 2) ? w2
                   : (ti == 3) ? w3 : (ti == 4) ? w4 : w5;
    const float4* wv = (const float4*)(w + boff);
    float m = 0.f;
#pragma unroll
    for (int k = 0; k < 4; k++) {
        float4 v = wv[threadIdx.x + k * 256];
        m = fmaxf(m, fmaxf(fmaxf(fabsf(v.x), fabsf(v.y)), fmaxf(fabsf(v.z), fabsf(v.w))));
    }
#pragma unroll
    for (int o = 32; o > 0; o >>= 1) m = fmaxf(m, __shfl_xor(m, o));
    if ((threadIdx.x & 63) == 0)
        atomicMax(scales + (7 + ti) * PSPREAD + ((b * 4 + (threadIdx.x >> 6)) & (PSPREAD - 1)),
                  __float_as_int(m));
}

// quantize (qdq) + transpose weight: W[K][N] fp32 -> Wt[N][K] bf16
__global__ __launch_bounds__(256) void wqt_k(const float* __restrict__ W, u16* __restrict__ Wt,
                                             int K, int N, const int* __restrict__ scales, int slot) {
    __shared__ float t[32][33];
    const int n0 = blockIdx.x * 32, k0 = blockIdx.y * 32;
    const float s = getscale64(scales, slot);
    const int c = threadIdx.x & 31, r0 = threadIdx.x >> 5;   // 8 rows per pass
#pragma unroll
    for (int i = 0; i < 4; i++) {
        int kk = k0 + r0 + i * 8;
        t[r0 + i * 8][c] = qdqv(W[(long)kk * N + n0 + c], s);
    }
    __syncthreads();
#pragma unroll
    for (int i = 0; i < 4; i++) {
        int nn = n0 + r0 + i * 8;
        Wt[(long)nn * K + k0 + c] = f2bf(t[c][r0 + i * 8]);
    }
}

// block reduction helper (256 threads, 4 waves)
__device__ __forceinline__ float blk_sum(float v, float* red) {
#pragma unroll
    for (int o = 32; o > 0; o >>= 1) v += __shfl_xor(v, o);
    __syncthreads();
    if ((threadIdx.x & 63) == 0) red[threadIdx.x >> 6] = v;
    __syncthreads();
    return red[0] + red[1] + red[2] + red[3];
}

// LayerNorm (eps=1e-6): fp32 in -> bf16 out (raw, pre-qdq), absmax -> slot
__global__ __launch_bounds__(256) void ln_k(const float* __restrict__ in, const float* __restrict__ gam,
                                            const float* __restrict__ bet, u16* __restrict__ out,
                                            int* __restrict__ scales, int slot) {
    __shared__ float red[4];
    const long row = blockIdx.x;
    const int tid = threadIdx.x;
    float4 v = ((const float4*)(in + row * 1024))[tid];
    float mean = blk_sum(v.x + v.y + v.z + v.w, red) * (1.f / 1024.f);
    float dx = v.x - mean, dy = v.y - mean, dz = v.z - mean, dw = v.w - mean;
    float var = blk_sum(dx * dx + dy * dy + dz * dz + dw * dw, red) * (1.f / 1024.f);
    float inv = rsqrtf(var + 1e-6f);
    float4 gg = ((const float4*)gam)[tid];
    float4 bb = ((const float4*)bet)[tid];
    float o0 = dx * inv * gg.x + bb.x, o1 = dy * inv * gg.y + bb.y;
    float o2 = dz * inv * gg.z + bb.z, o3 = dw * inv * gg.w + bb.w;
    ushort4 st;
    st.x = f2bf(o0); st.y = f2bf(o1); st.z = f2bf(o2); st.w = f2bf(o3);
    ((ushort4*)(out + row * 1024))[tid] = st;
    float am = fmaxf(fmaxf(fabsf(o0), fabsf(o1)), fmaxf(fabsf(o2), fabsf(o3)));
#pragma unroll
    for (int o = 32; o > 0; o >>= 1) am = fmaxf(am, __shfl_xor(am, o));
    if ((tid & 63) == 0)
        atomicMax(scales + slot * PSPREAD + ((blockIdx.x * 4 + (tid >> 6)) & (PSPREAD - 1)),
                  __float_as_int(am));
}

// in-place elementwise qdq on a bf16 buffer (8 elems / thread)
__global__ void qact_k(u16* buf, int n8, const int* __restrict__ scales, int slot) {
    const float s = getscale64(scales, slot);     // uniform, before any early-out
    int i = blockIdx.x * 256 + threadIdx.x;
    if (i >= n8) return;
    uint4 u = ((const uint4*)buf)[i];
    unsigned w[4] = {u.x, u.y, u.z, u.w};
#pragma unroll
    for (int j = 0; j < 4; j++) {
        float lo = qdqv(bf2f((u16)(w[j] & 0xFFFFu)), s);
        float hi = qdqv(bf2f((u16)(w[j] >> 16)), s);
        w[j] = (unsigned)f2bf(lo) | ((unsigned)f2bf(hi) << 16);
    }
    uint4 o; o.x = w[0]; o.y = w[1]; o.z = w[2]; o.w = w[3];
    ((uint4*)buf)[i] = o;
}

// qdq + transpose V: v[B*H][S][32] bf16 -> vt[B*H][32][S] bf16
__global__ __launch_bounds__(256) void vtrans_k(const u16* __restrict__ v, u16* __restrict__ vt,
                                                const int* __restrict__ scales) {
    __shared__ u16 t[32][33];
    const int bh = blockIdx.y, s0 = blockIdx.x * 32;
    const float s = getscale64(scales, 3);
    const int c = threadIdx.x & 31, r0 = threadIdx.x >> 5;
    const u16* src = v + ((long)bh * 1024 + s0) * 32;
#pragma unroll
    for (int i = 0; i < 4; i++) {
        int r = r0 + i * 8;
        t[r][c] = f2bf(qdqv(bf2f(src[r * 32 + c]), s));
    }
    __syncthreads();
    u16* dst = vt + (long)bh * 32768;
#pragma unroll
    for (int i = 0; i < 4; i++) {
        int r = r0 + i * 8;                       // d index
        dst[(long)r * 1024 + s0 + c] = t[c][r];
    }
}

// ---------------------------------------------------------------------------
// GEMM: C[M][N] = A[M][K](bf16, pre-qdq) * Bt[N][K](bf16, pre-qdq)^T + bias
// 128x128 tile, BK=32, 256 threads (4 waves in 2x2), m97-style staging.
// EPI 0: QKV (blockIdx.z selects Wt/bias/out/slot), scatter [B,H,S,HD] + absmax
// EPI 1: + resid -> fp32                       (Wo + residual)
// EPI 2: gelu(tanh) -> bf16 + absmax           (W1)
// EPI 3: -> fp32                               (W2, final out)
// ---------------------------------------------------------------------------
template <int EPI>
__global__ __launch_bounds__(256, 2) void gemm_k(const u16* __restrict__ A, const u16* __restrict__ Bt,
                                                 const float* __restrict__ bias, const float* __restrict__ bias2,
                                                 const float* __restrict__ bias3, int M, int N, int K,
                                                 float* __restrict__ outf, u16* __restrict__ outb,
                                                 const float* __restrict__ resid,
                                                 int* __restrict__ scales, int slot) {
    __shared__ u16 As[128 * 32];
    __shared__ u16 Bs[128 * 32];
    const float* bp = bias;
    if (EPI == 0) {
        const int z = blockIdx.z;
        Bt += (long)z * 1048576;                  // wtq/wtk/wtv contiguous
        outb += (long)z * 4194304;                // qb/kb/vb contiguous
        bp = (z == 0) ? bias : (z == 1 ? bias2 : bias3);
        slot += z;
    }
    const int tid = threadIdx.x;
    const int lane = tid & 63;
    const int wave = tid >> 6;
    const int wm = wave >> 1, wn = wave & 1;
    const int bm = blockIdx.y * 128, bn = blockIdx.x * 128;
    const int g = lane >> 4, c = lane & 15;

    const long astride = (long)K * 2;             // bytes per row
    const int srow = wave * 32 + (lane >> 2);     // staging row (+ i*16)
    const char* Ag = (const char*)A + (long)(bm + srow) * astride + (lane & 3) * 16;
    const char* Bg = (const char*)Bt + (long)(bn + srow) * astride + (lane & 3) * 16;
    char* Al = (char*)As + (wave * 32) * 64;      // wave-uniform LDS dest
    char* Bl = (char*)Bs + (wave * 32) * 64;

    f32x4 acc[4][4];
    const f32x4 zf = {0.f, 0.f, 0.f, 0.f};
#pragma unroll
    for (int i = 0; i < 4; i++)
#pragma unroll
        for (int j = 0; j < 4; j++) acc[i][j] = zf;

    const int nk = K >> 5;
    for (int kt = 0; kt < nk; ++kt) {
        __syncthreads();                          // protect LDS from prior reads
        const long ko = (long)kt * 64;
        gld16(Ag + ko, Al);
        gld16(Ag + ko + 16 * astride, Al + 1024);
        gld16(Bg + ko, Bl);
        gld16(Bg + ko + 16 * astride, Bl + 1024);
        __syncthreads();                          // vmcnt(0) drain before barrier

        bf16x8 af[4], bq[4];
#pragma unroll
        for (int i = 0; i < 4; i++)
            af[i] = *(const bf16x8*)((const char*)As + (wm * 64 + i * 16 + c) * 64 + g * 16);
#pragma unroll
        for (int j = 0; j < 4; j++)
            bq[j] = *(const bf16x8*)((const char*)Bs + (wn * 64 + j * 16 + c) * 64 + g * 16);
#pragma unroll
        for (int i = 0; i < 4; i++)
#pragma unroll
            for (int j = 0; j < 4; j++)
                acc[i][j] = MFMA(af[i], bq[j], acc[i][j]);
    }

    float am = 0.f;
#pragma unroll
    for (int i = 0; i < 4; i++) {
#pragma unroll
        for (int j = 0; j < 4; j++) {
#pragma unroll
            for (int t = 0; t < 4; t++) {
                const int row = bm + wm * 64 + i * 16 + g * 4 + t;
                const int col = bn + wn * 64 + j * 16 + c;
                float v = acc[i][j][t] + bp[col];
                if (EPI == 0) {
                    // [B*S][H*HD] -> [B,H,S,HD]
                    long oi = ((long)((row >> 10) * 32 + (col >> 5))) * 32768
                              + (long)(row & 1023) * 32 + (col & 31);
                    outb[oi] = f2bf(v);
                    am = fmaxf(am, fabsf(v));
                } else if (EPI == 1) {
                    long oi = (long)row * N + col;
                    outf[oi] = v + resid[oi];
                } else if (EPI == 2) {
                    float t3 = v * v * v;
                    float gl = 0.5f * v * (1.f + tanhf(0.79788456080286536f * (v + 0.044715f * t3)));
                    outb[(long)row * N + col] = f2bf(gl);
                    am = fmaxf(am, fabsf(gl));
                } else {
                    outf[(long)row * N + col] = v;
                }
            }
        }
    }
    if (EPI == 0 || EPI == 2) {
#pragma unroll
        for (int o = 32; o > 0; o >>= 1) am = fmaxf(am, __shfl_xor(am, o));
        if (lane == 0)
            atomicMax(scales + slot * PSPREAD
                          + (((blockIdx.x + blockIdx.y * gridDim.x) * 4 + wave) & (PSPREAD - 1)),
                      __float_as_int(am));
    }
}

// ---------------------------------------------------------------------------
// Attention v2: per block = 1 wave, 32 q-rows of one (b,h). Swapped QK^T:
// s = mfma(K_tile, Q) -> D[row=k][col=q], so each lane holds 8 scores of ONE
// q-row; softmax reduce = 7 local fmax + 2 shuffles (xor16/32). rel bias is
// uniform (rel[0]/rel[64]) for all k-tiles with |kk-q0| >= 64 -> fast path.
// P repacked via LDS (stride 40 u16, ~4-way banks) into the PV A-fragment.
// ---------------------------------------------------------------------------
__global__ __launch_bounds__(64) void attn_k(const u16* __restrict__ q, const u16* __restrict__ k,
                                             const u16* __restrict__ vt, const float* __restrict__ relpos,
                                             u16* __restrict__ attn, int* __restrict__ scales) {
    __shared__ float rel_s[65];                   // rel[d]*scale for this head
    __shared__ u16 P[32 * 40];                    // P tile, padded stride
    __shared__ float frs[32];                     // fr / l cross-layout transfer
    const int lane = threadIdx.x;
    const int bh = blockIdx.y;
    const int b = bh >> 5, h = bh & 31;
    const int q0 = blockIdx.x * 32;
    const int g = lane >> 4, c = lane & 15;
    const float SC = 0.03125f;                    // 1/(sqrt(32)*1024^0.25)
    for (int i = lane; i < 65; i += 64) rel_s[i] = relpos[i * 32 + h] * SC;
    __syncthreads();
    const float rb0 = rel_s[0], rb64 = rel_s[64];

    const u16* qb = q + ((long)bh * 1024 + q0) * 32;
    const u16* kb = k + (long)bh * 32768;
    const u16* vb = vt + (long)bh * 32768;

    bf16x8 aq[2];                                 // Q as B-fragment: col=q, k=d
#pragma unroll
    for (int i = 0; i < 2; i++) aq[i] = *(const bf16x8*)(qb + (i * 16 + c) * 32 + g * 8);

    const f32x4 zf = {0.f, 0.f, 0.f, 0.f};
    f32x4 o[2][2] = {{zf, zf}, {zf, zf}};         // row=q(g*4+t), col=d(j*16+c)
    float m_run[2] = {-1e30f, -1e30f};            // per q=i*16+c (replicated x4 g)
    float l_run[2] = {0.f, 0.f};

    for (int kt = 0; kt < 32; ++kt) {
        const int kk = kt * 32;
        // K rows as A-fragment: row=k, k-dim=d
        bf16x8 bk0 = *(const bf16x8*)(kb + (kk + c) * 32 + g * 8);
        bf16x8 bk1 = *(const bf16x8*)(kb + (kk + 16 + c) * 32 + g * 8);
        // V^T as B-fragment: col=d, k-dim=s
        bf16x8 bv0 = *(const bf16x8*)(vb + c * 1024 + kk + g * 8);
        bf16x8 bv1 = *(const bf16x8*)(vb + (16 + c) * 1024 + kk + g * 8);
        const int mode = (kk >= q0 + 64) ? 0 : (kk <= q0 - 64) ? 1 : 2;  // uniform

#pragma unroll
        for (int i = 0; i < 2; i++) {
            f32x4 s0 = MFMA(bk0, aq[i], zf);      // lane: q=i*16+c, k=kk+g*4+t
            f32x4 s1 = MFMA(bk1, aq[i], zf);      // k=kk+16+g*4+t
            float v[8];
            if (mode == 0) {
#pragma unroll
                for (int t = 0; t < 4; t++) { v[t] = fmaf(s0[t], SC, rb0); v[4 + t] = fmaf(s1[t], SC, rb0); }
            } else if (mode == 1) {
#pragma unroll
                for (int t = 0; t < 4; t++) { v[t] = fmaf(s0[t], SC, rb64); v[4 + t] = fmaf(s1[t], SC, rb64); }
            } else {
                const int base = (q0 + i * 16 + c) - kk - g * 4 + 32;
#pragma unroll
                for (int t = 0; t < 4; t++) {
                    int d0 = min(max(base - t, 0), 64);
                    int d1 = min(max(base - 16 - t, 0), 64);
                    v[t] = fmaf(s0[t], SC, rel_s[d0]);
                    v[4 + t] = fmaf(s1[t], SC, rel_s[d1]);
                }
            }
            float mt = fmaxf(fmaxf(fmaxf(v[0], v[1]), fmaxf(v[2], v[3])),
                             fmaxf(fmaxf(v[4], v[5]), fmaxf(v[6], v[7])));
            mt = fmaxf(mt, __shfl_xor(mt, 16));
            mt = fmaxf(mt, __shfl_xor(mt, 32));
            const float mn = fmaxf(m_run[i], mt);
            const float fr = __expf(m_run[i] - mn);
            float sm = 0.f;
            bf16x4 pk0, pk1;
#pragma unroll
            for (int t = 0; t < 4; t++) {
                float p = __expf(v[t] - mn);     sm += p; pk0[t] = (__bf16)p;
                float p2 = __expf(v[4 + t] - mn); sm += p2; pk1[t] = (__bf16)p2;
            }
            sm += __shfl_xor(sm, 16);
            sm += __shfl_xor(sm, 32);
            l_run[i] = l_run[i] * fr + sm;
            m_run[i] = mn;
            *(bf16x4*)&P[(i * 16 + c) * 40 + g * 4] = pk0;
            *(bf16x4*)&P[(i * 16 + c) * 40 + 16 + g * 4] = pk1;
            if (g == 0) frs[i * 16 + c] = fr;
        }
        // rescale o by fr (per-q broadcast via LDS) and accumulate PV
        float4 f0 = *(float4*)&frs[g * 4];
        float4 f1 = *(float4*)&frs[16 + g * 4];
#pragma unroll
        for (int j = 0; j < 2; j++) {
            o[0][j][0] *= f0.x; o[0][j][1] *= f0.y; o[0][j][2] *= f0.z; o[0][j][3] *= f0.w;
            o[1][j][0] *= f1.x; o[1][j][1] *= f1.y; o[1][j][2] *= f1.z; o[1][j][3] *= f1.w;
        }
        bf16x8 ap0 = *(const bf16x8*)&P[c * 40 + g * 8];
        bf16x8 ap1 = *(const bf16x8*)&P[(16 + c) * 40 + g * 8];
        o[0][0] = MFMA(ap0, bv0, o[0][0]);
        o[0][1] = MFMA(ap0, bv1, o[0][1]);
        o[1][0] = MFMA(ap1, bv0, o[1][0]);
        o[1][1] = MFMA(ap1, bv1, o[1][1]);
    }

    // final: l per q -> o layout via LDS, divide, store, absmax
    if (g == 0) { frs[c] = l_run[0]; frs[16 + c] = l_run[1]; }
    float4 l0 = *(float4*)&frs[g * 4];
    float4 l1 = *(float4*)&frs[16 + g * 4];
    float lv[2][4] = {{l0.x, l0.y, l0.z, l0.w}, {l1.x, l1.y, l1.z, l1.w}};
    float am = 0.f;
#pragma unroll
    for (int i = 0; i < 2; i++)
#pragma unroll
        for (int j = 0; j < 2; j++)
#pragma unroll
            for (int t = 0; t < 4; t++) {
                float val = o[i][j][t] / (lv[i][t] + 1e-6f);
                long row = (long)b * 1024 + q0 + i * 16 + g * 4 + t;
                attn[row * 1024 + h * 32 + j * 16 + c] = f2bf(val);
                am = fmaxf(am, fabsf(val));
            }
#pragma unroll
    for (int o2 = 32; o2 > 0; o2 >>= 1) am = fmaxf(am, __shfl_xor(am, o2));
    if (lane == 0)
        atomicMax(scales + 4 * PSPREAD + ((blockIdx.x + blockIdx.y * 32) & (PSPREAD - 1)),
                  __float_as_int(am));
}

// ---------------------------------------------------------------------------
extern "C" void kernel_launch(void* const* d_in, const int* in_sizes, int n_in,
                              void* d_out, int out_size, void* d_ws, size_t ws_size,
                              hipStream_t stream) {
    (void)in_sizes; (void)n_in; (void)out_size; (void)ws_size;
    const float* inputs = (const float*)d_in[0];
    const float* ln1s   = (const float*)d_in[1];
    const float* ln1b   = (const float*)d_in[2];
    const float* Wq     = (const float*)d_in[3];
    const float* bq     = (const float*)d_in[4];
    const float* Wk     = (const float*)d_in[5];
    const float* bk     = (const float*)d_in[6];
    const float* Wv     = (const float*)d_in[7];
    const float* bv     = (const float*)d_in[8];
    const float* rel    = (const float*)d_in[9];
    const float* Wo     = (const float*)d_in[10];
    const float* bo     = (const float*)d_in[11];
    const float* ln2s   = (const float*)d_in[12];
    const float* ln2b   = (const float*)d_in[13];
    const float* W1     = (const float*)d_in[14];
    const float* b1     = (const float*)d_in[15];
    const float* W2     = (const float*)d_in[16];
    const float* b2     = (const float*)d_in[17];
    float* out = (float*)d_out;

    // workspace layout (88 MB + 4 KB), with aliasing:
    //   [scales 4KB][q 8M][k 8M][v 8M][vt 8M][xq/attn 8M][xr 16M][y 8M][Wt 24M]
    //   h (32MB) aliases q..vt after attention+Wo are done.
    char* ws = (char*)d_ws;
    int* scales = (int*)ws;
    u16* qb   = (u16*)(ws + 4096);
    u16* kbuf = qb + 4194304;
    u16* vbuf = kbuf + 4194304;
    u16* vtb  = vbuf + 4194304;
    u16* hb   = qb;                       // alias (32MB region)
    u16* xq   = vtb + 4194304;
    u16* attnb = xq;                      // alias (xq dead after QKV gemms)
    float* xr = (float*)(xq + 4194304);
    u16* yb   = (u16*)(xr + 4194304);
    u16* wtq  = yb + 4194304;
    u16* wtk  = wtq + 1048576;
    u16* wtv  = wtk + 1048576;
    u16* wto  = wtv + 1048576;
    u16* wt1  = wto + 1048576;
    u16* wt2  = wt1 + 4194304;

    // slots: 0=x 1=q 2=k 3=v 4=attn 5=y 6=h 7..12=Wq,Wk,Wv,Wo,W1,W2
    zero_k<<<1, 1024, 0, stream>>>(scales);
    wabsmax6_k<<<3072, 256, 0, stream>>>(Wq, Wk, Wv, Wo, W1, W2, scales);

    ln_k<<<4096, 256, 0, stream>>>(inputs, ln1s, ln1b, xq, scales, 0);

    wqt_k<<<dim3(32, 32), 256, 0, stream>>>(Wq, wtq, 1024, 1024, scales, 7);
    wqt_k<<<dim3(32, 32), 256, 0, stream>>>(Wk, wtk, 1024, 1024, scales, 8);
    wqt_k<<<dim3(32, 32), 256, 0, stream>>>(Wv, wtv, 1024, 1024, scales, 9);
    wqt_k<<<dim3(32, 32), 256, 0, stream>>>(Wo, wto, 1024, 1024, scales, 10);
    wqt_k<<<dim3(128, 32), 256, 0, stream>>>(W1, wt1, 1024, 4096, scales, 11);
    wqt_k<<<dim3(32, 128), 256, 0, stream>>>(W2, wt2, 4096, 1024, scales, 12);

    qact_k<<<2048, 256, 0, stream>>>(xq, 524288, scales, 0);

    // fused QKV: blockIdx.z picks weight/bias/out/slot
    gemm_k<0><<<dim3(8, 32, 3), 256, 0, stream>>>(xq, wtq, bq, bk, bv, 4096, 1024, 1024,
                                                  nullptr, qb, nullptr, scales, 1);

    qact_k<<<2048, 256, 0, stream>>>(qb, 524288, scales, 1);
    qact_k<<<2048, 256, 0, stream>>>(kbuf, 524288, scales, 2);
    vtrans_k<<<dim3(32, 128), 256, 0, stream>>>(vbuf, vtb, scales);

    attn_k<<<dim3(32, 128), 64, 0, stream>>>(qb, kbuf, vtb, rel, attnb, scales);
    qact_k<<<2048, 256, 0, stream>>>(attnb, 524288, scales, 4);

    gemm_k<1><<<dim3(8, 32), 256, 0, stream>>>(attnb, wto, bo, nullptr, nullptr, 4096, 1024, 1024,
                                               xr, nullptr, inputs, scales, -1);

    ln_k<<<4096, 256, 0, stream>>>(xr, ln2s, ln2b, yb, scales, 5);
    qact_k<<<2048, 256, 0, stream>>>(yb, 524288, scales, 5);

    gemm_k<2><<<dim3(32, 32), 256, 0, stream>>>(yb, wt1, b1, nullptr, nullptr, 4096, 4096, 1024,
                                                nullptr, hb, nullptr, scales, 6);
    qact_k<<<8192, 256, 0, stream>>>(hb, 2097152, scales, 6);

    gemm_k<3><<<dim3(8, 32), 256, 0, stream>>>(hb, wt2, b2, nullptr, nullptr, 4096, 1024, 4096,
                                               out, nullptr, nullptr, scales, -1);
}

// Round 4
// 497.669 us; speedup vs baseline: 2.1268x; 1.1027x over previous
//
#include <hip/hip_runtime.h>
#include <cstdint>

// ---------------------------------------------------------------------------
// TransformerBlock: LN1 -> qdq -> QKV gemms -> attn(relpos bias) -> Wo gemm
//  -> +resid -> LN2 -> W1 gemm -> gelu(tanh) -> W2 gemm.
// R1: hierarchical absmax (64 partial slots/scale, spread atomics).
// R2: swapped-QK^T attention, uniform-rel-bias fast path, fused QKV gemm.
// R3: BK=64 GEMM core with XOR-swizzled LDS (rule-21: inverse-swz source +
//     linear gld16 dest + swz ds_read); split-K=2 for Wo and W2 (1 block/CU
//     -> 2); Wo combine fused into LN2 (kills xr round-trip); wqt6/qact2
//     launch fusion.
// ---------------------------------------------------------------------------

typedef unsigned short u16;
typedef __bf16 bf16x4 __attribute__((ext_vector_type(4)));
typedef __bf16 bf16x8 __attribute__((ext_vector_type(8)));
typedef float  f32x4  __attribute__((ext_vector_type(4)));

#define MFMA(a, b, c) __builtin_amdgcn_mfma_f32_16x16x32_bf16(a, b, c, 0, 0, 0)

#define NSLOT 13
#define PSPREAD 64   // partial slots per logical scale

__device__ __forceinline__ float bf2f(u16 h) {
    return __uint_as_float(((unsigned)h) << 16);
}
__device__ __forceinline__ u16 f2bf(float f) {   // RNE
    unsigned u = __float_as_uint(f);
    u += 0x7FFFu + ((u >> 16) & 1u);
    return (u16)(u >> 16);
}
__device__ __forceinline__ float qdqv(float v, float s) {
    float q = rintf(v / s);                       // rint = RNE, matches jnp.round
    q = fminf(fmaxf(q, -127.f), 127.f);
    return q * s;
}

// wave-cooperative: reduce the 64 partial absmax ints of `slot` -> scale.
__device__ __forceinline__ float getscale64(const int* scales, int slot) {
    float m = __int_as_float(scales[slot * PSPREAD + (threadIdx.x & 63)]);
#pragma unroll
    for (int o = 32; o > 0; o >>= 1) m = fmaxf(m, __shfl_xor(m, o));
    return fmaxf(m / 127.f, 1e-8f);
}

// global -> LDS direct (16B per lane; LDS dest is wave-uniform base + lane*16)
typedef const __attribute__((address_space(1))) unsigned gas_u32;
typedef __attribute__((address_space(3))) unsigned las_u32;
__device__ __forceinline__ void gld16(const void* g, void* l) {
    __builtin_amdgcn_global_load_lds((gas_u32*)g, (las_u32*)l, 16, 0, 0);
}

// ---------------------------------------------------------------------------
__global__ void zero_k(int* s) {
    if (threadIdx.x < NSLOT * PSPREAD) s[threadIdx.x] = 0;
}

// fused absmax of the six weight tensors -> slots 7..12 (one launch).
__global__ __launch_bounds__(256) void wabsmax6_k(const float* __restrict__ w0, const float* __restrict__ w1,
                                                  const float* __restrict__ w2, const float* __restrict__ w3,
                                                  const float* __restrict__ w4, const float* __restrict__ w5,
                                                  int* scales) {
    const int b = blockIdx.x;
    int ti, boff;
    if (b < 1024)      { ti = b >> 8; boff = (b & 255) * 4096; }
    else if (b < 2048) { ti = 4;      boff = (b - 1024) * 4096; }
    else               { ti = 5;      boff = (b - 2048) * 4096; }
    const float* w = (ti == 0) ? w0 : (ti == 1) ? w1 : (ti == 2) ? w2
                   : (ti == 3) ? w3 : (ti == 4) ? w4 : w5;
    const float4* wv = (const float4*)(w + boff);
    float m = 0.f;
#pragma unroll
    for (int k = 0; k < 4; k++) {
        float4 v = wv[threadIdx.x + k * 256];
        m = fmaxf(m, fmaxf(fmaxf(fabsf(v.x), fabsf(v.y)), fmaxf(fabsf(v.z), fabsf(v.w))));
    }
#pragma unroll
    for (int o = 32; o > 0; o >>= 1) m = fmaxf(m, __shfl_xor(m, o));
    if ((threadIdx.x & 63) == 0)
        atomicMax(scales + (7 + ti) * PSPREAD + ((b * 4 + (threadIdx.x >> 6)) & (PSPREAD - 1)),
                  __float_as_int(m));
}

// fused quantize+transpose of all six weights: W[K][N] fp32 -> Wt[N][K] bf16.
// wtbase layout: wtq,wtk,wtv,wto (1M u16 each), wt1 (4M), wt2 (4M).
__global__ __launch_bounds__(256) void wqt6_k(const float* __restrict__ w0, const float* __restrict__ w1,
                                              const float* __restrict__ w2, const float* __restrict__ w3,
                                              const float* __restrict__ w4, const float* __restrict__ w5,
                                              u16* __restrict__ wtbase, const int* __restrict__ scales) {
    __shared__ float t[32][33];
    const int b = blockIdx.x;
    const float* W;
    u16* Wt;
    int K, N, bx, by, slot;
    if (b < 4096) {
        const int ti = b >> 10, r = b & 1023;
        W = (ti == 0) ? w0 : (ti == 1) ? w1 : (ti == 2) ? w2 : w3;
        Wt = wtbase + (long)ti * 1048576;
        K = 1024; N = 1024; bx = r & 31; by = r >> 5; slot = 7 + ti;
    } else if (b < 8192) {
        const int r = b - 4096;
        W = w4; Wt = wtbase + 4194304;
        K = 1024; N = 4096; bx = r & 127; by = r >> 7; slot = 11;
    } else {
        const int r = b - 8192;
        W = w5; Wt = wtbase + 8388608;
        K = 4096; N = 1024; bx = r & 31; by = r >> 5; slot = 12;
    }
    const int n0 = bx * 32, k0 = by * 32;
    const float s = getscale64(scales, slot);
    const int c = threadIdx.x & 31, r0 = threadIdx.x >> 5;
#pragma unroll
    for (int i = 0; i < 4; i++) {
        int kk = k0 + r0 + i * 8;
        t[r0 + i * 8][c] = qdqv(W[(long)kk * N + n0 + c], s);
    }
    __syncthreads();
#pragma unroll
    for (int i = 0; i < 4; i++) {
        int nn = n0 + r0 + i * 8;
        Wt[(long)nn * K + k0 + c] = f2bf(t[c][r0 + i * 8]);
    }
}

// block reduction helper (256 threads, 4 waves)
__device__ __forceinline__ float blk_sum(float v, float* red) {
#pragma unroll
    for (int o = 32; o > 0; o >>= 1) v += __shfl_xor(v, o);
    __syncthreads();
    if ((threadIdx.x & 63) == 0) red[threadIdx.x >> 6] = v;
    __syncthreads();
    return red[0] + red[1] + red[2] + red[3];
}

// LayerNorm (eps=1e-6): fp32 in -> bf16 out (raw, pre-qdq), absmax -> slot
__global__ __launch_bounds__(256) void ln_k(const float* __restrict__ in, const float* __restrict__ gam,
                                            const float* __restrict__ bet, u16* __restrict__ out,
                                            int* __restrict__ scales, int slot) {
    __shared__ float red[4];
    const long row = blockIdx.x;
    const int tid = threadIdx.x;
    float4 v = ((const float4*)(in + row * 1024))[tid];
    float mean = blk_sum(v.x + v.y + v.z + v.w, red) * (1.f / 1024.f);
    float dx = v.x - mean, dy = v.y - mean, dz = v.z - mean, dw = v.w - mean;
    float var = blk_sum(dx * dx + dy * dy + dz * dz + dw * dw, red) * (1.f / 1024.f);
    float inv = rsqrtf(var + 1e-6f);
    float4 gg = ((const float4*)gam)[tid];
    float4 bb = ((const float4*)bet)[tid];
    float o0 = dx * inv * gg.x + bb.x, o1 = dy * inv * gg.y + bb.y;
    float o2 = dz * inv * gg.z + bb.z, o3 = dw * inv * gg.w + bb.w;
    ushort4 st;
    st.x = f2bf(o0); st.y = f2bf(o1); st.z = f2bf(o2); st.w = f2bf(o3);
    ((ushort4*)(out + row * 1024))[tid] = st;
    float am = fmaxf(fmaxf(fabsf(o0), fabsf(o1)), fmaxf(fabsf(o2), fabsf(o3)));
#pragma unroll
    for (int o = 32; o > 0; o >>= 1) am = fmaxf(am, __shfl_xor(am, o));
    if ((tid & 63) == 0)
        atomicMax(scales + slot * PSPREAD + ((blockIdx.x * 4 + (tid >> 6)) & (PSPREAD - 1)),
                  __float_as_int(am));
}

// Wo-combine + residual + LayerNorm2 fused: v = p0+p1+bo+inputs, LN -> yb.
__global__ __launch_bounds__(256) void ln2comb_k(const float* __restrict__ p, const float* __restrict__ bo,
                                                 const float* __restrict__ inputs,
                                                 const float* __restrict__ gam, const float* __restrict__ bet,
                                                 u16* __restrict__ out, int* __restrict__ scales) {
    __shared__ float red[4];
    const long row = blockIdx.x;
    const int tid = threadIdx.x;
    float4 a = ((const float4*)(p + row * 1024))[tid];
    float4 b = ((const float4*)(p + 4194304 + row * 1024))[tid];
    float4 bb0 = ((const float4*)bo)[tid];
    float4 xi = ((const float4*)(inputs + row * 1024))[tid];
    float4 v;
    v.x = a.x + b.x + bb0.x + xi.x; v.y = a.y + b.y + bb0.y + xi.y;
    v.z = a.z + b.z + bb0.z + xi.z; v.w = a.w + b.w + bb0.w + xi.w;
    float mean = blk_sum(v.x + v.y + v.z + v.w, red) * (1.f / 1024.f);
    float dx = v.x - mean, dy = v.y - mean, dz = v.z - mean, dw = v.w - mean;
    float var = blk_sum(dx * dx + dy * dy + dz * dz + dw * dw, red) * (1.f / 1024.f);
    float inv = rsqrtf(var + 1e-6f);
    float4 gg = ((const float4*)gam)[tid];
    float4 bb = ((const float4*)bet)[tid];
    float o0 = dx * inv * gg.x + bb.x, o1 = dy * inv * gg.y + bb.y;
    float o2 = dz * inv * gg.z + bb.z, o3 = dw * inv * gg.w + bb.w;
    ushort4 st;
    st.x = f2bf(o0); st.y = f2bf(o1); st.z = f2bf(o2); st.w = f2bf(o3);
    ((ushort4*)(out + row * 1024))[tid] = st;
    float am = fmaxf(fmaxf(fabsf(o0), fabsf(o1)), fmaxf(fabsf(o2), fabsf(o3)));
#pragma unroll
    for (int o = 32; o > 0; o >>= 1) am = fmaxf(am, __shfl_xor(am, o));
    if ((tid & 63) == 0)
        atomicMax(scales + 5 * PSPREAD + ((blockIdx.x * 4 + (tid >> 6)) & (PSPREAD - 1)),
                  __float_as_int(am));
}

// W2-combine: out = p0 + p1 + b2   (4M floats, final output)
__global__ void combo_k(const float* __restrict__ p, const float* __restrict__ b2,
                        float* __restrict__ out) {
    const int i = blockIdx.x * 256 + threadIdx.x;   // float4 index, 1M total
    float4 a = ((const float4*)p)[i];
    float4 b = ((const float4*)(p + 4194304))[i];
    float4 bb = ((const float4*)b2)[i & 255];
    float4 o;
    o.x = a.x + b.x + bb.x; o.y = a.y + b.y + bb.y;
    o.z = a.z + b.z + bb.z; o.w = a.w + b.w + bb.w;
    ((float4*)out)[i] = o;
}

// in-place elementwise qdq on a bf16 buffer (8 elems / thread)
__global__ void qact_k(u16* buf, int n8, const int* __restrict__ scales, int slot) {
    const float s = getscale64(scales, slot);     // uniform, before any early-out
    int i = blockIdx.x * 256 + threadIdx.x;
    if (i >= n8) return;
    uint4 u = ((const uint4*)buf)[i];
    unsigned w[4] = {u.x, u.y, u.z, u.w};
#pragma unroll
    for (int j = 0; j < 4; j++) {
        float lo = qdqv(bf2f((u16)(w[j] & 0xFFFFu)), s);
        float hi = qdqv(bf2f((u16)(w[j] >> 16)), s);
        w[j] = (unsigned)f2bf(lo) | ((unsigned)f2bf(hi) << 16);
    }
    uint4 o; o.x = w[0]; o.y = w[1]; o.z = w[2]; o.w = w[3];
    ((uint4*)buf)[i] = o;
}

// q and k buffers in one launch (contiguous; slots 1,2). grid 4096.
__global__ void qact2_k(u16* buf, const int* __restrict__ scales) {
    const int i = blockIdx.x * 256 + threadIdx.x;       // uint4 index
    const int slot = (i >= 524288) ? 2 : 1;             // block-uniform
    const float s = getscale64(scales, slot);
    uint4 u = ((const uint4*)buf)[i];
    unsigned w[4] = {u.x, u.y, u.z, u.w};
#pragma unroll
    for (int j = 0; j < 4; j++) {
        float lo = qdqv(bf2f((u16)(w[j] & 0xFFFFu)), s);
        float hi = qdqv(bf2f((u16)(w[j] >> 16)), s);
        w[j] = (unsigned)f2bf(lo) | ((unsigned)f2bf(hi) << 16);
    }
    uint4 o; o.x = w[0]; o.y = w[1]; o.z = w[2]; o.w = w[3];
    ((uint4*)buf)[i] = o;
}

// qdq + transpose V: v[B*H][S][32] bf16 -> vt[B*H][32][S] bf16
__global__ __launch_bounds__(256) void vtrans_k(const u16* __restrict__ v, u16* __restrict__ vt,
                                                const int* __restrict__ scales) {
    __shared__ u16 t[32][33];
    const int bh = blockIdx.y, s0 = blockIdx.x * 32;
    const float s = getscale64(scales, 3);
    const int c = threadIdx.x & 31, r0 = threadIdx.x >> 5;
    const u16* src = v + ((long)bh * 1024 + s0) * 32;
#pragma unroll
    for (int i = 0; i < 4; i++) {
        int r = r0 + i * 8;
        t[r][c] = f2bf(qdqv(bf2f(src[r * 32 + c]), s));
    }
    __syncthreads();
    u16* dst = vt + (long)bh * 32768;
#pragma unroll
    for (int i = 0; i < 4; i++) {
        int r = r0 + i * 8;                       // d index
        dst[(long)r * 1024 + s0 + c] = t[c][r];
    }
}

// ---------------------------------------------------------------------------
// GEMM: C[M][N] = A[M][K](bf16) * Bt[N][K](bf16)^T, 128x128 tile, BK=64,
// 256 threads (2x2 waves). LDS XOR-swizzle (rule-21): linear gld16 dest,
// inverse-swizzled global source, swizzled ds_read -> conflict-free b128.
// EPI 0: QKV (blockIdx.z = tensor), scatter [B,H,S,HD] bf16 + absmax
// EPI 2: gelu(tanh) -> bf16 + absmax           (W1)
// EPI 4: split-K partial (blockIdx.z = k-slice), raw fp32, no bias
// ---------------------------------------------------------------------------
template <int EPI>
__global__ __launch_bounds__(256, 2) void gemm_k(const u16* __restrict__ A, const u16* __restrict__ Bt,
                                                 const float* __restrict__ bias, const float* __restrict__ bias2,
                                                 const float* __restrict__ bias3,
                                                 int M, int N, int Kfull, int Kslice,
                                                 float* __restrict__ outf, u16* __restrict__ outb,
                                                 int* __restrict__ scales, int slot) {
    __shared__ u16 As[128 * 64];                  // 16KB
    __shared__ u16 Bs[128 * 64];                  // 16KB
    const float* bp = bias;
    long koff = 0, ooff = 0;
    if (EPI == 0) {
        const int z = blockIdx.z;
        Bt += (long)z * 1048576;                  // wtq/wtk/wtv contiguous
        outb += (long)z * 4194304;                // qb/kb/vb contiguous
        bp = (z == 0) ? bias : (z == 1 ? bias2 : bias3);
        slot += z;
    }
    if (EPI == 4) {
        koff = (long)blockIdx.z * Kslice * 2;     // byte offset into K
        ooff = (long)blockIdx.z * M * N;          // partial-buffer offset
    }
    const int tid = threadIdx.x;
    const int lane = tid & 63;
    const int wave = tid >> 6;
    const int wm = wave >> 1, wn = wave & 1;
    const int bm = blockIdx.y * 128, bn = blockIdx.x * 128;
    const int g = lane >> 4, c = lane & 15;

    const long astride = (long)Kfull * 2;         // bytes per row
    // staging: 8 lanes per 128B row-chunk; source pre-swizzled so linear LDS
    // dest yields XOR-swizzled layout (involution: cb ^ ((row&7)<<4)).
    const int srow = wave * 32 + (lane >> 3);
    const int scol = ((lane & 7) * 16) ^ ((lane >> 3) << 4);
    const char* Ag = (const char*)A + (long)(bm + srow) * astride + scol + koff;
    const char* Bg = (const char*)Bt + (long)(bn + srow) * astride + scol + koff;
    char* Al = (char*)As + wave * 4096;           // wave-uniform LDS dest
    char* Bl = (char*)Bs + wave * 4096;

    f32x4 acc[4][4];
    const f32x4 zf = {0.f, 0.f, 0.f, 0.f};
#pragma unroll
    for (int i = 0; i < 4; i++)
#pragma unroll
        for (int j = 0; j < 4; j++) acc[i][j] = zf;

    const int nk = Kslice >> 6;
    for (int kt = 0; kt < nk; ++kt) {
        __syncthreads();                          // protect LDS from prior reads
        const long ko = (long)kt * 128;
#pragma unroll
        for (int i = 0; i < 4; i++) gld16(Ag + ko + (long)(i * 8) * astride, Al + i * 1024);
#pragma unroll
        for (int i = 0; i < 4; i++) gld16(Bg + ko + (long)(i * 8) * astride, Bl + i * 1024);
        __syncthreads();                          // vmcnt(0) drain before barrier

#pragma unroll
        for (int kh = 0; kh < 2; kh++) {
            bf16x8 af[4], bq[4];
            const int kb = kh * 64 + g * 16;
            const int sw = kb ^ ((c & 7) << 4);   // swizzled read offset
#pragma unroll
            for (int i = 0; i < 4; i++)
                af[i] = *(const bf16x8*)((const char*)As + (wm * 64 + i * 16 + c) * 128 + sw);
#pragma unroll
            for (int j = 0; j < 4; j++)
                bq[j] = *(const bf16x8*)((const char*)Bs + (wn * 64 + j * 16 + c) * 128 + sw);
#pragma unroll
            for (int i = 0; i < 4; i++)
#pragma unroll
                for (int j = 0; j < 4; j++)
                    acc[i][j] = MFMA(af[i], bq[j], acc[i][j]);
        }
    }

    float am = 0.f;
#pragma unroll
    for (int i = 0; i < 4; i++) {
#pragma unroll
        for (int j = 0; j < 4; j++) {
#pragma unroll
            for (int t = 0; t < 4; t++) {
                const int row = bm + wm * 64 + i * 16 + g * 4 + t;
                const int col = bn + wn * 64 + j * 16 + c;
                if (EPI == 0) {
                    float v = acc[i][j][t] + bp[col];
                    // [B*S][H*HD] -> [B,H,S,HD]
                    long oi = ((long)((row >> 10) * 32 + (col >> 5))) * 32768
                              + (long)(row & 1023) * 32 + (col & 31);
                    outb[oi] = f2bf(v);
                    am = fmaxf(am, fabsf(v));
                } else if (EPI == 2) {
                    float v = acc[i][j][t] + bp[col];
                    float t3 = v * v * v;
                    float gl = 0.5f * v * (1.f + tanhf(0.79788456080286536f * (v + 0.044715f * t3)));
                    outb[(long)row * N + col] = f2bf(gl);
                    am = fmaxf(am, fabsf(gl));
                } else {                          // EPI 4: raw partial
                    outf[ooff + (long)row * N + col] = acc[i][j][t];
                }
            }
        }
    }
    if (EPI == 0 || EPI == 2) {
#pragma unroll
        for (int o = 32; o > 0; o >>= 1) am = fmaxf(am, __shfl_xor(am, o));
        if (lane == 0)
            atomicMax(scales + slot * PSPREAD
                          + (((blockIdx.x + blockIdx.y * gridDim.x) * 4 + wave) & (PSPREAD - 1)),
                      __float_as_int(am));
    }
}

// ---------------------------------------------------------------------------
// Attention v2 (R2): swapped QK^T, lane-local softmax, uniform-bias fast path.
// ---------------------------------------------------------------------------
__global__ __launch_bounds__(64) void attn_k(const u16* __restrict__ q, const u16* __restrict__ k,
                                             const u16* __restrict__ vt, const float* __restrict__ relpos,
                                             u16* __restrict__ attn, int* __restrict__ scales) {
    __shared__ float rel_s[65];                   // rel[d]*scale for this head
    __shared__ u16 P[32 * 40];                    // P tile, padded stride
    __shared__ float frs[32];                     // fr / l cross-layout transfer
    const int lane = threadIdx.x;
    const int bh = blockIdx.y;
    const int b = bh >> 5, h = bh & 31;
    const int q0 = blockIdx.x * 32;
    const int g = lane >> 4, c = lane & 15;
    const float SC = 0.03125f;                    // 1/(sqrt(32)*1024^0.25)
    for (int i = lane; i < 65; i += 64) rel_s[i] = relpos[i * 32 + h] * SC;
    __syncthreads();
    const float rb0 = rel_s[0], rb64 = rel_s[64];

    const u16* qb = q + ((long)bh * 1024 + q0) * 32;
    const u16* kb = k + (long)bh * 32768;
    const u16* vb = vt + (long)bh * 32768;

    bf16x8 aq[2];                                 // Q as B-fragment: col=q, k=d
#pragma unroll
    for (int i = 0; i < 2; i++) aq[i] = *(const bf16x8*)(qb + (i * 16 + c) * 32 + g * 8);

    const f32x4 zf = {0.f, 0.f, 0.f, 0.f};
    f32x4 o[2][2] = {{zf, zf}, {zf, zf}};         // row=q(g*4+t), col=d(j*16+c)
    float m_run[2] = {-1e30f, -1e30f};            // per q=i*16+c (replicated x4 g)
    float l_run[2] = {0.f, 0.f};

    for (int kt = 0; kt < 32; ++kt) {
        const int kk = kt * 32;
        bf16x8 bk0 = *(const bf16x8*)(kb + (kk + c) * 32 + g * 8);
        bf16x8 bk1 = *(const bf16x8*)(kb + (kk + 16 + c) * 32 + g * 8);
        bf16x8 bv0 = *(const bf16x8*)(vb + c * 1024 + kk + g * 8);
        bf16x8 bv1 = *(const bf16x8*)(vb + (16 + c) * 1024 + kk + g * 8);
        const int mode = (kk >= q0 + 64) ? 0 : (kk <= q0 - 64) ? 1 : 2;

#pragma unroll
        for (int i = 0; i < 2; i++) {
            f32x4 s0 = MFMA(bk0, aq[i], zf);      // lane: q=i*16+c, k=kk+g*4+t
            f32x4 s1 = MFMA(bk1, aq[i], zf);      // k=kk+16+g*4+t
            float v[8];
            if (mode == 0) {
#pragma unroll
                for (int t = 0; t < 4; t++) { v[t] = fmaf(s0[t], SC, rb0); v[4 + t] = fmaf(s1[t], SC, rb0); }
            } else if (mode == 1) {
#pragma unroll
                for (int t = 0; t < 4; t++) { v[t] = fmaf(s0[t], SC, rb64); v[4 + t] = fmaf(s1[t], SC, rb64); }
            } else {
                const int base = (q0 + i * 16 + c) - kk - g * 4 + 32;
#pragma unroll
                for (int t = 0; t < 4; t++) {
                    int d0 = min(max(base - t, 0), 64);
                    int d1 = min(max(base - 16 - t, 0), 64);
                    v[t] = fmaf(s0[t], SC, rel_s[d0]);
                    v[4 + t] = fmaf(s1[t], SC, rel_s[d1]);
                }
            }
            float mt = fmaxf(fmaxf(fmaxf(v[0], v[1]), fmaxf(v[2], v[3])),
                             fmaxf(fmaxf(v[4], v[5]), fmaxf(v[6], v[7])));
            mt = fmaxf(mt, __shfl_xor(mt, 16));
            mt = fmaxf(mt, __shfl_xor(mt, 32));
            const float mn = fmaxf(m_run[i], mt);
            const float fr = __expf(m_run[i] - mn);
            float sm = 0.f;
            bf16x4 pk0, pk1;
#pragma unroll
            for (int t = 0; t < 4; t++) {
                float p = __expf(v[t] - mn);     sm += p; pk0[t] = (__bf16)p;
                float p2 = __expf(v[4 + t] - mn); sm += p2; pk1[t] = (__bf16)p2;
            }
            sm += __shfl_xor(sm, 16);
            sm += __shfl_xor(sm, 32);
            l_run[i] = l_run[i] * fr + sm;
            m_run[i] = mn;
            *(bf16x4*)&P[(i * 16 + c) * 40 + g * 4] = pk0;
            *(bf16x4*)&P[(i * 16 + c) * 40 + 16 + g * 4] = pk1;
            if (g == 0) frs[i * 16 + c] = fr;
        }
        float4 f0 = *(float4*)&frs[g * 4];
        float4 f1 = *(float4*)&frs[16 + g * 4];
#pragma unroll
        for (int j = 0; j < 2; j++) {
            o[0][j][0] *= f0.x; o[0][j][1] *= f0.y; o[0][j][2] *= f0.z; o[0][j][3] *= f0.w;
            o[1][j][0] *= f1.x; o[1][j][1] *= f1.y; o[1][j][2] *= f1.z; o[1][j][3] *= f1.w;
        }
        bf16x8 ap0 = *(const bf16x8*)&P[c * 40 + g * 8];
        bf16x8 ap1 = *(const bf16x8*)&P[(16 + c) * 40 + g * 8];
        o[0][0] = MFMA(ap0, bv0, o[0][0]);
        o[0][1] = MFMA(ap0, bv1, o[0][1]);
        o[1][0] = MFMA(ap1, bv0, o[1][0]);
        o[1][1] = MFMA(ap1, bv1, o[1][1]);
    }

    if (g == 0) { frs[c] = l_run[0]; frs[16 + c] = l_run[1]; }
    float4 l0 = *(float4*)&frs[g * 4];
    float4 l1 = *(float4*)&frs[16 + g * 4];
    float lv[2][4] = {{l0.x, l0.y, l0.z, l0.w}, {l1.x, l1.y, l1.z, l1.w}};
    float am = 0.f;
#pragma unroll
    for (int i = 0; i < 2; i++)
#pragma unroll
        for (int j = 0; j < 2; j++)
#pragma unroll
            for (int t = 0; t < 4; t++) {
                float val = o[i][j][t] / (lv[i][t] + 1e-6f);
                long row = (long)b * 1024 + q0 + i * 16 + g * 4 + t;
                attn[row * 1024 + h * 32 + j * 16 + c] = f2bf(val);
                am = fmaxf(am, fabsf(val));
            }
#pragma unroll
    for (int o2 = 32; o2 > 0; o2 >>= 1) am = fmaxf(am, __shfl_xor(am, o2));
    if (lane == 0)
        atomicMax(scales + 4 * PSPREAD + ((blockIdx.x + blockIdx.y * 32) & (PSPREAD - 1)),
                  __float_as_int(am));
}

// ---------------------------------------------------------------------------
extern "C" void kernel_launch(void* const* d_in, const int* in_sizes, int n_in,
                              void* d_out, int out_size, void* d_ws, size_t ws_size,
                              hipStream_t stream) {
    (void)in_sizes; (void)n_in; (void)out_size; (void)ws_size;
    const float* inputs = (const float*)d_in[0];
    const float* ln1s   = (const float*)d_in[1];
    const float* ln1b   = (const float*)d_in[2];
    const float* Wq     = (const float*)d_in[3];
    const float* bq     = (const float*)d_in[4];
    const float* Wk     = (const float*)d_in[5];
    const float* bk     = (const float*)d_in[6];
    const float* Wv     = (const float*)d_in[7];
    const float* bv     = (const float*)d_in[8];
    const float* rel    = (const float*)d_in[9];
    const float* Wo     = (const float*)d_in[10];
    const float* bo     = (const float*)d_in[11];
    const float* ln2s   = (const float*)d_in[12];
    const float* ln2b   = (const float*)d_in[13];
    const float* W1     = (const float*)d_in[14];
    const float* b1     = (const float*)d_in[15];
    const float* W2     = (const float*)d_in[16];
    const float* b2     = (const float*)d_in[17];
    float* out = (float*)d_out;

    // workspace layout (88 MB + 4 KB), time-multiplexed:
    //  regionA (32MB): q/k/v/vt  ->  Wo partials (2x16MB)  ->  h (32MB)
    //  regionB (32MB): xq/attnb(8) + y(8) + spare  ->  W2 partials (2x16MB)
    //  regionC (24MB): wtq,wtk,wtv,wto (2MB ea), wt1 (8MB), wt2 (8MB)
    char* ws = (char*)d_ws;
    int* scales = (int*)ws;
    char* regionA = ws + 4096;
    char* regionB = regionA + (32u << 20);
    char* regionC = regionB + (32u << 20);
    u16* qb    = (u16*)regionA;
    u16* kbuf  = qb + 4194304;
    u16* vbuf  = kbuf + 4194304;
    u16* vtb   = vbuf + 4194304;
    float* pWo = (float*)regionA;          // after attn: q/k/v/vt dead
    u16* hb    = (u16*)regionA;            // after ln2comb: partials dead
    u16* xq    = (u16*)regionB;
    u16* attnb = xq;                       // xq dead after QKV gemm
    u16* yb    = xq + 4194304;
    float* pW2 = (float*)regionB;          // after W1 gemm: xq/yb dead
    u16* wtb   = (u16*)regionC;            // wtq..wt2 contiguous

    // slots: 0=x 1=q 2=k 3=v 4=attn 5=y 6=h 7..12=Wq,Wk,Wv,Wo,W1,W2
    zero_k<<<1, 1024, 0, stream>>>(scales);
    wabsmax6_k<<<3072, 256, 0, stream>>>(Wq, Wk, Wv, Wo, W1, W2, scales);

    ln_k<<<4096, 256, 0, stream>>>(inputs, ln1s, ln1b, xq, scales, 0);

    wqt6_k<<<12288, 256, 0, stream>>>(Wq, Wk, Wv, Wo, W1, W2, wtb, scales);

    qact_k<<<2048, 256, 0, stream>>>(xq, 524288, scales, 0);

    // fused QKV: blockIdx.z picks weight/bias/out/slot
    gemm_k<0><<<dim3(8, 32, 3), 256, 0, stream>>>(xq, wtb, bq, bk, bv, 4096, 1024, 1024, 1024,
                                                  nullptr, qb, scales, 1);

    qact2_k<<<4096, 256, 0, stream>>>(qb, scales);          // q (slot1) + k (slot2)
    vtrans_k<<<dim3(32, 128), 256, 0, stream>>>(vbuf, vtb, scales);

    attn_k<<<dim3(32, 128), 64, 0, stream>>>(qb, kbuf, vtb, rel, attnb, scales);
    qact_k<<<2048, 256, 0, stream>>>(attnb, 524288, scales, 4);

    // Wo: split-K=2 partials (regionA), combine fused into LN2
    gemm_k<4><<<dim3(8, 32, 2), 256, 0, stream>>>(attnb, wtb + 3145728, nullptr, nullptr, nullptr,
                                                  4096, 1024, 1024, 512, pWo, nullptr, scales, -1);
    ln2comb_k<<<4096, 256, 0, stream>>>(pWo, bo, inputs, ln2s, ln2b, yb, scales);
    qact_k<<<2048, 256, 0, stream>>>(yb, 524288, scales, 5);

    // W1: 4096x4096x1024, gelu epilogue
    gemm_k<2><<<dim3(32, 32), 256, 0, stream>>>(yb, wtb + 4194304, b1, nullptr, nullptr,
                                                4096, 4096, 1024, 1024, nullptr, hb, scales, 6);
    qact_k<<<8192, 256, 0, stream>>>(hb, 2097152, scales, 6);

    // W2: split-K=2 partials (regionB), combine -> out
    gemm_k<4><<<dim3(8, 32, 2), 256, 0, stream>>>(hb, wtb + 8388608, nullptr, nullptr, nullptr,
                                                  4096, 1024, 4096, 2048, pW2, nullptr, scales, -1);
    combo_k<<<4096, 256, 0, stream>>>(pW2, b2, out);
}

// Round 5
// 317.426 us; speedup vs baseline: 3.3344x; 1.5678x over previous
//
#include <hip/hip_runtime.h>
#include <cstdint>

// ---------------------------------------------------------------------------
// TransformerBlock: LN1 -> qdq -> QKV gemms -> attn(relpos bias) -> Wo gemm
//  -> +resid -> LN2 -> W1 gemm -> gelu(tanh) -> W2 gemm.
// R1: hierarchical absmax partials.  R2: swapped-QK^T attn, fused QKV gemm.
// R3: BK=64 swizzled GEMM, split-K Wo/W2, LN2+combine fusion.
// R4: atomicMax partials strided to 64B (L2 atomics serialize PER CACHE LINE,
//     not per address: R1's 64 consecutive ints = 2 lines -> only 2.3x).
//     Per-block (not per-wave) atomic commit in ln_k/ln2comb_k.
// ---------------------------------------------------------------------------

typedef unsigned short u16;
typedef __bf16 bf16x4 __attribute__((ext_vector_type(4)));
typedef __bf16 bf16x8 __attribute__((ext_vector_type(8)));
typedef float  f32x4  __attribute__((ext_vector_type(4)));

#define MFMA(a, b, c) __builtin_amdgcn_mfma_f32_16x16x32_bf16(a, b, c, 0, 0, 0)

#define NSLOT 13
#define PSPREAD 64       // partial slots per logical scale
#define PSTRIDE 16       // ints between partials (64B -> distinct L2 lines)
#define SLOTSZ (PSPREAD * PSTRIDE)   // 1024 ints per logical slot

__device__ __forceinline__ float bf2f(u16 h) {
    return __uint_as_float(((unsigned)h) << 16);
}
__device__ __forceinline__ u16 f2bf(float f) {   // RNE
    unsigned u = __float_as_uint(f);
    u += 0x7FFFu + ((u >> 16) & 1u);
    return (u16)(u >> 16);
}
__device__ __forceinline__ float qdqv(float v, float s) {
    float q = rintf(v / s);                       // rint = RNE, matches jnp.round
    q = fminf(fmaxf(q, -127.f), 127.f);
    return q * s;
}

// wave-cooperative: reduce the 64 partial absmax ints of `slot` -> scale.
__device__ __forceinline__ float getscale64(const int* scales, int slot) {
    float m = __int_as_float(scales[slot * SLOTSZ + (threadIdx.x & 63) * PSTRIDE]);
#pragma unroll
    for (int o = 32; o > 0; o >>= 1) m = fmaxf(m, __shfl_xor(m, o));
    return fmaxf(m / 127.f, 1e-8f);
}

// global -> LDS direct (16B per lane; LDS dest is wave-uniform base + lane*16)
typedef const __attribute__((address_space(1))) unsigned gas_u32;
typedef __attribute__((address_space(3))) unsigned las_u32;
__device__ __forceinline__ void gld16(const void* g, void* l) {
    __builtin_amdgcn_global_load_lds((gas_u32*)g, (las_u32*)l, 16, 0, 0);
}

// ---------------------------------------------------------------------------
__global__ void zero_k(int* s) {
    const int i = blockIdx.x * 256 + threadIdx.x;
    if (i < NSLOT * SLOTSZ) s[i] = 0;
}

// fused absmax of the six weight tensors -> slots 7..12 (one launch).
__global__ __launch_bounds__(256) void wabsmax6_k(const float* __restrict__ w0, const float* __restrict__ w1,
                                                  const float* __restrict__ w2, const float* __restrict__ w3,
                                                  const float* __restrict__ w4, const float* __restrict__ w5,
                                                  int* scales) {
    const int b = blockIdx.x;
    int ti, boff;
    if (b < 1024)      { ti = b >> 8; boff = (b & 255) * 4096; }
    else if (b < 2048) { ti = 4;      boff = (b - 1024) * 4096; }
    else               { ti = 5;      boff = (b - 2048) * 4096; }
    const float* w = (ti == 0) ? w0 : (ti == 1) ? w1 : (ti == 2) ? w2
                   : (ti == 3) ? w3 : (ti == 4) ? w4 : w5;
    const float4* wv = (const float4*)(w + boff);
    float m = 0.f;
#pragma unroll
    for (int k = 0; k < 4; k++) {
        float4 v = wv[threadIdx.x + k * 256];
        m = fmaxf(m, fmaxf(fmaxf(fabsf(v.x), fabsf(v.y)), fmaxf(fabsf(v.z), fabsf(v.w))));
    }
#pragma unroll
    for (int o = 32; o > 0; o >>= 1) m = fmaxf(m, __shfl_xor(m, o));
    if ((threadIdx.x & 63) == 0)
        atomicMax(scales + (7 + ti) * SLOTSZ + (((b * 4 + (threadIdx.x >> 6)) & (PSPREAD - 1)) * PSTRIDE),
                  __float_as_int(m));
}

// fused quantize+transpose of all six weights: W[K][N] fp32 -> Wt[N][K] bf16.
// wtbase layout: wtq,wtk,wtv,wto (1M u16 each), wt1 (4M), wt2 (4M).
__global__ __launch_bounds__(256) void wqt6_k(const float* __restrict__ w0, const float* __restrict__ w1,
                                              const float* __restrict__ w2, const float* __restrict__ w3,
                                              const float* __restrict__ w4, const float* __restrict__ w5,
                                              u16* __restrict__ wtbase, const int* __restrict__ scales) {
    __shared__ float t[32][33];
    const int b = blockIdx.x;
    const float* W;
    u16* Wt;
    int K, N, bx, by, slot;
    if (b < 4096) {
        const int ti = b >> 10, r = b & 1023;
        W = (ti == 0) ? w0 : (ti == 1) ? w1 : (ti == 2) ? w2 : w3;
        Wt = wtbase + (long)ti * 1048576;
        K = 1024; N = 1024; bx = r & 31; by = r >> 5; slot = 7 + ti;
    } else if (b < 8192) {
        const int r = b - 4096;
        W = w4; Wt = wtbase + 4194304;
        K = 1024; N = 4096; bx = r & 127; by = r >> 7; slot = 11;
    } else {
        const int r = b - 8192;
        W = w5; Wt = wtbase + 8388608;
        K = 4096; N = 1024; bx = r & 31; by = r >> 5; slot = 12;
    }
    const int n0 = bx * 32, k0 = by * 32;
    const float s = getscale64(scales, slot);
    const int c = threadIdx.x & 31, r0 = threadIdx.x >> 5;
#pragma unroll
    for (int i = 0; i < 4; i++) {
        int kk = k0 + r0 + i * 8;
        t[r0 + i * 8][c] = qdqv(W[(long)kk * N + n0 + c], s);
    }
    __syncthreads();
#pragma unroll
    for (int i = 0; i < 4; i++) {
        int nn = n0 + r0 + i * 8;
        Wt[(long)nn * K + k0 + c] = f2bf(t[c][r0 + i * 8]);
    }
}

// block reduction helper (256 threads, 4 waves)
__device__ __forceinline__ float blk_sum(float v, float* red) {
#pragma unroll
    for (int o = 32; o > 0; o >>= 1) v += __shfl_xor(v, o);
    __syncthreads();
    if ((threadIdx.x & 63) == 0) red[threadIdx.x >> 6] = v;
    __syncthreads();
    return red[0] + red[1] + red[2] + red[3];
}

// block absmax commit: one atomic per block (line-strided partial slot)
__device__ __forceinline__ void blk_absmax_commit(float am, float* red, int* scales, int slot) {
#pragma unroll
    for (int o = 32; o > 0; o >>= 1) am = fmaxf(am, __shfl_xor(am, o));
    __syncthreads();                              // red[] reuse safety
    if ((threadIdx.x & 63) == 0) red[threadIdx.x >> 6] = am;
    __syncthreads();
    if (threadIdx.x == 0) {
        float m = fmaxf(fmaxf(red[0], red[1]), fmaxf(red[2], red[3]));
        atomicMax(scales + slot * SLOTSZ + ((blockIdx.x & (PSPREAD - 1)) * PSTRIDE),
                  __float_as_int(m));
    }
}

// LayerNorm (eps=1e-6): fp32 in -> bf16 out (raw, pre-qdq), absmax -> slot
__global__ __launch_bounds__(256) void ln_k(const float* __restrict__ in, const float* __restrict__ gam,
                                            const float* __restrict__ bet, u16* __restrict__ out,
                                            int* __restrict__ scales, int slot) {
    __shared__ float red[4];
    const long row = blockIdx.x;
    const int tid = threadIdx.x;
    float4 v = ((const float4*)(in + row * 1024))[tid];
    float mean = blk_sum(v.x + v.y + v.z + v.w, red) * (1.f / 1024.f);
    float dx = v.x - mean, dy = v.y - mean, dz = v.z - mean, dw = v.w - mean;
    float var = blk_sum(dx * dx + dy * dy + dz * dz + dw * dw, red) * (1.f / 1024.f);
    float inv = rsqrtf(var + 1e-6f);
    float4 gg = ((const float4*)gam)[tid];
    float4 bb = ((const float4*)bet)[tid];
    float o0 = dx * inv * gg.x + bb.x, o1 = dy * inv * gg.y + bb.y;
    float o2 = dz * inv * gg.z + bb.z, o3 = dw * inv * gg.w + bb.w;
    ushort4 st;
    st.x = f2bf(o0); st.y = f2bf(o1); st.z = f2bf(o2); st.w = f2bf(o3);
    ((ushort4*)(out + row * 1024))[tid] = st;
    float am = fmaxf(fmaxf(fabsf(o0), fabsf(o1)), fmaxf(fabsf(o2), fabsf(o3)));
    blk_absmax_commit(am, red, scales, slot);
}

// Wo-combine + residual + LayerNorm2 fused: v = p0+p1+bo+inputs, LN -> yb.
__global__ __launch_bounds__(256) void ln2comb_k(const float* __restrict__ p, const float* __restrict__ bo,
                                                 const float* __restrict__ inputs,
                                                 const float* __restrict__ gam, const float* __restrict__ bet,
                                                 u16* __restrict__ out, int* __restrict__ scales) {
    __shared__ float red[4];
    const long row = blockIdx.x;
    const int tid = threadIdx.x;
    float4 a = ((const float4*)(p + row * 1024))[tid];
    float4 b = ((const float4*)(p + 4194304 + row * 1024))[tid];
    float4 bb0 = ((const float4*)bo)[tid];
    float4 xi = ((const float4*)(inputs + row * 1024))[tid];
    float4 v;
    v.x = a.x + b.x + bb0.x + xi.x; v.y = a.y + b.y + bb0.y + xi.y;
    v.z = a.z + b.z + bb0.z + xi.z; v.w = a.w + b.w + bb0.w + xi.w;
    float mean = blk_sum(v.x + v.y + v.z + v.w, red) * (1.f / 1024.f);
    float dx = v.x - mean, dy = v.y - mean, dz = v.z - mean, dw = v.w - mean;
    float var = blk_sum(dx * dx + dy * dy + dz * dz + dw * dw, red) * (1.f / 1024.f);
    float inv = rsqrtf(var + 1e-6f);
    float4 gg = ((const float4*)gam)[tid];
    float4 bb = ((const float4*)bet)[tid];
    float o0 = dx * inv * gg.x + bb.x, o1 = dy * inv * gg.y + bb.y;
    float o2 = dz * inv * gg.z + bb.z, o3 = dw * inv * gg.w + bb.w;
    ushort4 st;
    st.x = f2bf(o0); st.y = f2bf(o1); st.z = f2bf(o2); st.w = f2bf(o3);
    ((ushort4*)(out + row * 1024))[tid] = st;
    float am = fmaxf(fmaxf(fabsf(o0), fabsf(o1)), fmaxf(fabsf(o2), fabsf(o3)));
    blk_absmax_commit(am, red, scales, 5);
}

// W2-combine: out = p0 + p1 + b2   (4M floats, final output)
__global__ void combo_k(const float* __restrict__ p, const float* __restrict__ b2,
                        float* __restrict__ out) {
    const int i = blockIdx.x * 256 + threadIdx.x;   // float4 index, 1M total
    float4 a = ((const float4*)p)[i];
    float4 b = ((const float4*)(p + 4194304))[i];
    float4 bb = ((const float4*)b2)[i & 255];
    float4 o;
    o.x = a.x + b.x + bb.x; o.y = a.y + b.y + bb.y;
    o.z = a.z + b.z + bb.z; o.w = a.w + b.w + bb.w;
    ((float4*)out)[i] = o;
}

// in-place elementwise qdq on a bf16 buffer (8 elems / thread)
__global__ void qact_k(u16* buf, int n8, const int* __restrict__ scales, int slot) {
    const float s = getscale64(scales, slot);     // uniform, before any early-out
    int i = blockIdx.x * 256 + threadIdx.x;
    if (i >= n8) return;
    uint4 u = ((const uint4*)buf)[i];
    unsigned w[4] = {u.x, u.y, u.z, u.w};
#pragma unroll
    for (int j = 0; j < 4; j++) {
        float lo = qdqv(bf2f((u16)(w[j] & 0xFFFFu)), s);
        float hi = qdqv(bf2f((u16)(w[j] >> 16)), s);
        w[j] = (unsigned)f2bf(lo) | ((unsigned)f2bf(hi) << 16);
    }
    uint4 o; o.x = w[0]; o.y = w[1]; o.z = w[2]; o.w = w[3];
    ((uint4*)buf)[i] = o;
}

// q and k buffers in one launch (contiguous; slots 1,2). grid 4096.
__global__ void qact2_k(u16* buf, const int* __restrict__ scales) {
    const int i = blockIdx.x * 256 + threadIdx.x;       // uint4 index
    const int slot = (i >= 524288) ? 2 : 1;             // block-uniform
    const float s = getscale64(scales, slot);
    uint4 u = ((const uint4*)buf)[i];
    unsigned w[4] = {u.x, u.y, u.z, u.w};
#pragma unroll
    for (int j = 0; j < 4; j++) {
        float lo = qdqv(bf2f((u16)(w[j] & 0xFFFFu)), s);
        float hi = qdqv(bf2f((u16)(w[j] >> 16)), s);
        w[j] = (unsigned)f2bf(lo) | ((unsigned)f2bf(hi) << 16);
    }
    uint4 o; o.x = w[0]; o.y = w[1]; o.z = w[2]; o.w = w[3];
    ((uint4*)buf)[i] = o;
}

// qdq + transpose V: v[B*H][S][32] bf16 -> vt[B*H][32][S] bf16
__global__ __launch_bounds__(256) void vtrans_k(const u16* __restrict__ v, u16* __restrict__ vt,
                                                const int* __restrict__ scales) {
    __shared__ u16 t[32][33];
    const int bh = blockIdx.y, s0 = blockIdx.x * 32;
    const float s = getscale64(scales, 3);
    const int c = threadIdx.x & 31, r0 = threadIdx.x >> 5;
    const u16* src = v + ((long)bh * 1024 + s0) * 32;
#pragma unroll
    for (int i = 0; i < 4; i++) {
        int r = r0 + i * 8;
        t[r][c] = f2bf(qdqv(bf2f(src[r * 32 + c]), s));
    }
    __syncthreads();
    u16* dst = vt + (long)bh * 32768;
#pragma unroll
    for (int i = 0; i < 4; i++) {
        int r = r0 + i * 8;                       // d index
        dst[(long)r * 1024 + s0 + c] = t[c][r];
    }
}

// ---------------------------------------------------------------------------
// GEMM: C[M][N] = A[M][K](bf16) * Bt[N][K](bf16)^T, 128x128 tile, BK=64,
// 256 threads (2x2 waves). LDS XOR-swizzle (rule-21): linear gld16 dest,
// inverse-swizzled global source, swizzled ds_read -> conflict-free b128.
// EPI 0: QKV (blockIdx.z = tensor), scatter [B,H,S,HD] bf16 + absmax
// EPI 2: gelu(tanh) -> bf16 + absmax           (W1)
// EPI 4: split-K partial (blockIdx.z = k-slice), raw fp32, no bias
// ---------------------------------------------------------------------------
template <int EPI>
__global__ __launch_bounds__(256, 2) void gemm_k(const u16* __restrict__ A, const u16* __restrict__ Bt,
                                                 const float* __restrict__ bias, const float* __restrict__ bias2,
                                                 const float* __restrict__ bias3,
                                                 int M, int N, int Kfull, int Kslice,
                                                 float* __restrict__ outf, u16* __restrict__ outb,
                                                 int* __restrict__ scales, int slot) {
    __shared__ u16 As[128 * 64];                  // 16KB
    __shared__ u16 Bs[128 * 64];                  // 16KB
    const float* bp = bias;
    long koff = 0, ooff = 0;
    if (EPI == 0) {
        const int z = blockIdx.z;
        Bt += (long)z * 1048576;                  // wtq/wtk/wtv contiguous
        outb += (long)z * 4194304;                // qb/kb/vb contiguous
        bp = (z == 0) ? bias : (z == 1 ? bias2 : bias3);
        slot += z;
    }
    if (EPI == 4) {
        koff = (long)blockIdx.z * Kslice * 2;     // byte offset into K
        ooff = (long)blockIdx.z * M * N;          // partial-buffer offset
    }
    const int tid = threadIdx.x;
    const int lane = tid & 63;
    const int wave = tid >> 6;
    const int wm = wave >> 1, wn = wave & 1;
    const int bm = blockIdx.y * 128, bn = blockIdx.x * 128;
    const int g = lane >> 4, c = lane & 15;

    const long astride = (long)Kfull * 2;         // bytes per row
    // staging: 8 lanes per 128B row-chunk; source pre-swizzled so linear LDS
    // dest yields XOR-swizzled layout (involution: cb ^ ((row&7)<<4)).
    const int srow = wave * 32 + (lane >> 3);
    const int scol = ((lane & 7) * 16) ^ ((lane >> 3) << 4);
    const char* Ag = (const char*)A + (long)(bm + srow) * astride + scol + koff;
    const char* Bg = (const char*)Bt + (long)(bn + srow) * astride + scol + koff;
    char* Al = (char*)As + wave * 4096;           // wave-uniform LDS dest
    char* Bl = (char*)Bs + wave * 4096;

    f32x4 acc[4][4];
    const f32x4 zf = {0.f, 0.f, 0.f, 0.f};
#pragma unroll
    for (int i = 0; i < 4; i++)
#pragma unroll
        for (int j = 0; j < 4; j++) acc[i][j] = zf;

    const int nk = Kslice >> 6;
    for (int kt = 0; kt < nk; ++kt) {
        __syncthreads();                          // protect LDS from prior reads
        const long ko = (long)kt * 128;
#pragma unroll
        for (int i = 0; i < 4; i++) gld16(Ag + ko + (long)(i * 8) * astride, Al + i * 1024);
#pragma unroll
        for (int i = 0; i < 4; i++) gld16(Bg + ko + (long)(i * 8) * astride, Bl + i * 1024);
        __syncthreads();                          // vmcnt(0) drain before barrier

#pragma unroll
        for (int kh = 0; kh < 2; kh++) {
            bf16x8 af[4], bq[4];
            const int kb = kh * 64 + g * 16;
            const int sw = kb ^ ((c & 7) << 4);   // swizzled read offset
#pragma unroll
            for (int i = 0; i < 4; i++)
                af[i] = *(const bf16x8*)((const char*)As + (wm * 64 + i * 16 + c) * 128 + sw);
#pragma unroll
            for (int j = 0; j < 4; j++)
                bq[j] = *(const bf16x8*)((const char*)Bs + (wn * 64 + j * 16 + c) * 128 + sw);
#pragma unroll
            for (int i = 0; i < 4; i++)
#pragma unroll
                for (int j = 0; j < 4; j++)
                    acc[i][j] = MFMA(af[i], bq[j], acc[i][j]);
        }
    }

    float am = 0.f;
#pragma unroll
    for (int i = 0; i < 4; i++) {
#pragma unroll
        for (int j = 0; j < 4; j++) {
#pragma unroll
            for (int t = 0; t < 4; t++) {
                const int row = bm + wm * 64 + i * 16 + g * 4 + t;
                const int col = bn + wn * 64 + j * 16 + c;
                if (EPI == 0) {
                    float v = acc[i][j][t] + bp[col];
                    // [B*S][H*HD] -> [B,H,S,HD]
                    long oi = ((long)((row >> 10) * 32 + (col >> 5))) * 32768
                              + (long)(row & 1023) * 32 + (col & 31);
                    outb[oi] = f2bf(v);
                    am = fmaxf(am, fabsf(v));
                } else if (EPI == 2) {
                    float v = acc[i][j][t] + bp[col];
                    float t3 = v * v * v;
                    float gl = 0.5f * v * (1.f + tanhf(0.79788456080286536f * (v + 0.044715f * t3)));
                    outb[(long)row * N + col] = f2bf(gl);
                    am = fmaxf(am, fabsf(gl));
                } else {                          // EPI 4: raw partial
                    outf[ooff + (long)row * N + col] = acc[i][j][t];
                }
            }
        }
    }
    if (EPI == 0 || EPI == 2) {
#pragma unroll
        for (int o = 32; o > 0; o >>= 1) am = fmaxf(am, __shfl_xor(am, o));
        if (lane == 0)
            atomicMax(scales + slot * SLOTSZ
                          + ((((blockIdx.x + blockIdx.y * gridDim.x) * 4 + wave) & (PSPREAD - 1)) * PSTRIDE),
                      __float_as_int(am));
    }
}

// ---------------------------------------------------------------------------
// Attention v2 (R2): swapped QK^T, lane-local softmax, uniform-bias fast path.
// ---------------------------------------------------------------------------
__global__ __launch_bounds__(64) void attn_k(const u16* __restrict__ q, const u16* __restrict__ k,
                                             const u16* __restrict__ vt, const float* __restrict__ relpos,
                                             u16* __restrict__ attn, int* __restrict__ scales) {
    __shared__ float rel_s[65];                   // rel[d]*scale for this head
    __shared__ u16 P[32 * 40];                    // P tile, padded stride
    __shared__ float frs[32];                     // fr / l cross-layout transfer
    const int lane = threadIdx.x;
    const int bh = blockIdx.y;
    const int b = bh >> 5, h = bh & 31;
    const int q0 = blockIdx.x * 32;
    const int g = lane >> 4, c = lane & 15;
    const float SC = 0.03125f;                    // 1/(sqrt(32)*1024^0.25)
    for (int i = lane; i < 65; i += 64) rel_s[i] = relpos[i * 32 + h] * SC;
    __syncthreads();
    const float rb0 = rel_s[0], rb64 = rel_s[64];

    const u16* qb = q + ((long)bh * 1024 + q0) * 32;
    const u16* kb = k + (long)bh * 32768;
    const u16* vb = vt + (long)bh * 32768;

    bf16x8 aq[2];                                 // Q as B-fragment: col=q, k=d
#pragma unroll
    for (int i = 0; i < 2; i++) aq[i] = *(const bf16x8*)(qb + (i * 16 + c) * 32 + g * 8);

    const f32x4 zf = {0.f, 0.f, 0.f, 0.f};
    f32x4 o[2][2] = {{zf, zf}, {zf, zf}};         // row=q(g*4+t), col=d(j*16+c)
    float m_run[2] = {-1e30f, -1e30f};            // per q=i*16+c (replicated x4 g)
    float l_run[2] = {0.f, 0.f};

    for (int kt = 0; kt < 32; ++kt) {
        const int kk = kt * 32;
        bf16x8 bk0 = *(const bf16x8*)(kb + (kk + c) * 32 + g * 8);
        bf16x8 bk1 = *(const bf16x8*)(kb + (kk + 16 + c) * 32 + g * 8);
        bf16x8 bv0 = *(const bf16x8*)(vb + c * 1024 + kk + g * 8);
        bf16x8 bv1 = *(const bf16x8*)(vb + (16 + c) * 1024 + kk + g * 8);
        const int mode = (kk >= q0 + 64) ? 0 : (kk <= q0 - 64) ? 1 : 2;

#pragma unroll
        for (int i = 0; i < 2; i++) {
            f32x4 s0 = MFMA(bk0, aq[i], zf);      // lane: q=i*16+c, k=kk+g*4+t
            f32x4 s1 = MFMA(bk1, aq[i], zf);      // k=kk+16+g*4+t
            float v[8];
            if (mode == 0) {
#pragma unroll
                for (int t = 0; t < 4; t++) { v[t] = fmaf(s0[t], SC, rb0); v[4 + t] = fmaf(s1[t], SC, rb0); }
            } else if (mode == 1) {
#pragma unroll
                for (int t = 0; t < 4; t++) { v[t] = fmaf(s0[t], SC, rb64); v[4 + t] = fmaf(s1[t], SC, rb64); }
            } else {
                const int base = (q0 + i * 16 + c) - kk - g * 4 + 32;
#pragma unroll
                for (int t = 0; t < 4; t++) {
                    int d0 = min(max(base - t, 0), 64);
                    int d1 = min(max(base - 16 - t, 0), 64);
                    v[t] = fmaf(s0[t], SC, rel_s[d0]);
                    v[4 + t] = fmaf(s1[t], SC, rel_s[d1]);
                }
            }
            float mt = fmaxf(fmaxf(fmaxf(v[0], v[1]), fmaxf(v[2], v[3])),
                             fmaxf(fmaxf(v[4], v[5]), fmaxf(v[6], v[7])));
            mt = fmaxf(mt, __shfl_xor(mt, 16));
            mt = fmaxf(mt, __shfl_xor(mt, 32));
            const float mn = fmaxf(m_run[i], mt);
            const float fr = __expf(m_run[i] - mn);
            float sm = 0.f;
            bf16x4 pk0, pk1;
#pragma unroll
            for (int t = 0; t < 4; t++) {
                float p = __expf(v[t] - mn);     sm += p; pk0[t] = (__bf16)p;
                float p2 = __expf(v[4 + t] - mn); sm += p2; pk1[t] = (__bf16)p2;
            }
            sm += __shfl_xor(sm, 16);
            sm += __shfl_xor(sm, 32);
            l_run[i] = l_run[i] * fr + sm;
            m_run[i] = mn;
            *(bf16x4*)&P[(i * 16 + c) * 40 + g * 4] = pk0;
            *(bf16x4*)&P[(i * 16 + c) * 40 + 16 + g * 4] = pk1;
            if (g == 0) frs[i * 16 + c] = fr;
        }
        float4 f0 = *(float4*)&frs[g * 4];
        float4 f1 = *(float4*)&frs[16 + g * 4];
#pragma unroll
        for (int j = 0; j < 2; j++) {
            o[0][j][0] *= f0.x; o[0][j][1] *= f0.y; o[0][j][2] *= f0.z; o[0][j][3] *= f0.w;
            o[1][j][0] *= f1.x; o[1][j][1] *= f1.y; o[1][j][2] *= f1.z; o[1][j][3] *= f1.w;
        }
        bf16x8 ap0 = *(const bf16x8*)&P[c * 40 + g * 8];
        bf16x8 ap1 = *(const bf16x8*)&P[(16 + c) * 40 + g * 8];
        o[0][0] = MFMA(ap0, bv0, o[0][0]);
        o[0][1] = MFMA(ap0, bv1, o[0][1]);
        o[1][0] = MFMA(ap1, bv0, o[1][0]);
        o[1][1] = MFMA(ap1, bv1, o[1][1]);
    }

    if (g == 0) { frs[c] = l_run[0]; frs[16 + c] = l_run[1]; }
    float4 l0 = *(float4*)&frs[g * 4];
    float4 l1 = *(float4*)&frs[16 + g * 4];
    float lv[2][4] = {{l0.x, l0.y, l0.z, l0.w}, {l1.x, l1.y, l1.z, l1.w}};
    float am = 0.f;
#pragma unroll
    for (int i = 0; i < 2; i++)
#pragma unroll
        for (int j = 0; j < 2; j++)
#pragma unroll
            for (int t = 0; t < 4; t++) {
                float val = o[i][j][t] / (lv[i][t] + 1e-6f);
                long row = (long)b * 1024 + q0 + i * 16 + g * 4 + t;
                attn[row * 1024 + h * 32 + j * 16 + c] = f2bf(val);
                am = fmaxf(am, fabsf(val));
            }
#pragma unroll
    for (int o2 = 32; o2 > 0; o2 >>= 1) am = fmaxf(am, __shfl_xor(am, o2));
    if (lane == 0)
        atomicMax(scales + 4 * SLOTSZ + (((blockIdx.x + blockIdx.y * 32) & (PSPREAD - 1)) * PSTRIDE),
                  __float_as_int(am));
}

// ---------------------------------------------------------------------------
extern "C" void kernel_launch(void* const* d_in, const int* in_sizes, int n_in,
                              void* d_out, int out_size, void* d_ws, size_t ws_size,
                              hipStream_t stream) {
    (void)in_sizes; (void)n_in; (void)out_size; (void)ws_size;
    const float* inputs = (const float*)d_in[0];
    const float* ln1s   = (const float*)d_in[1];
    const float* ln1b   = (const float*)d_in[2];
    const float* Wq     = (const float*)d_in[3];
    const float* bq     = (const float*)d_in[4];
    const float* Wk     = (const float*)d_in[5];
    const float* bk     = (const float*)d_in[6];
    const float* Wv     = (const float*)d_in[7];
    const float* bv     = (const float*)d_in[8];
    const float* rel    = (const float*)d_in[9];
    const float* Wo     = (const float*)d_in[10];
    const float* bo     = (const float*)d_in[11];
    const float* ln2s   = (const float*)d_in[12];
    const float* ln2b   = (const float*)d_in[13];
    const float* W1     = (const float*)d_in[14];
    const float* b1     = (const float*)d_in[15];
    const float* W2     = (const float*)d_in[16];
    const float* b2     = (const float*)d_in[17];
    float* out = (float*)d_out;

    // workspace layout (88 MB + 64 KB), time-multiplexed:
    //  scales: 64 KB (13 slots x 64 partials x 64B line-stride)
    //  regionA (32MB): q/k/v/vt  ->  Wo partials (2x16MB)  ->  h (32MB)
    //  regionB (32MB): xq/attnb(8) + y(8) + spare  ->  W2 partials (2x16MB)
    //  regionC (24MB): wtq,wtk,wtv,wto (2MB ea), wt1 (8MB), wt2 (8MB)
    char* ws = (char*)d_ws;
    int* scales = (int*)ws;
    char* regionA = ws + 65536;
    char* regionB = regionA + (32u << 20);
    char* regionC = regionB + (32u << 20);
    u16* qb    = (u16*)regionA;
    u16* kbuf  = qb + 4194304;
    u16* vbuf  = kbuf + 4194304;
    u16* vtb   = vbuf + 4194304;
    float* pWo = (float*)regionA;          // after attn: q/k/v/vt dead
    u16* hb    = (u16*)regionA;            // after ln2comb: partials dead
    u16* xq    = (u16*)regionB;
    u16* attnb = xq;                       // xq dead after QKV gemm
    u16* yb    = xq + 4194304;
    float* pW2 = (float*)regionB;          // after W1 gemm: xq/yb dead
    u16* wtb   = (u16*)regionC;            // wtq..wt2 contiguous

    // slots: 0=x 1=q 2=k 3=v 4=attn 5=y 6=h 7..12=Wq,Wk,Wv,Wo,W1,W2
    zero_k<<<52, 256, 0, stream>>>(scales);
    wabsmax6_k<<<3072, 256, 0, stream>>>(Wq, Wk, Wv, Wo, W1, W2, scales);

    ln_k<<<4096, 256, 0, stream>>>(inputs, ln1s, ln1b, xq, scales, 0);

    wqt6_k<<<12288, 256, 0, stream>>>(Wq, Wk, Wv, Wo, W1, W2, wtb, scales);

    qact_k<<<2048, 256, 0, stream>>>(xq, 524288, scales, 0);

    // fused QKV: blockIdx.z picks weight/bias/out/slot
    gemm_k<0><<<dim3(8, 32, 3), 256, 0, stream>>>(xq, wtb, bq, bk, bv, 4096, 1024, 1024, 1024,
                                                  nullptr, qb, scales, 1);

    qact2_k<<<4096, 256, 0, stream>>>(qb, scales);          // q (slot1) + k (slot2)
    vtrans_k<<<dim3(32, 128), 256, 0, stream>>>(vbuf, vtb, scales);

    attn_k<<<dim3(32, 128), 64, 0, stream>>>(qb, kbuf, vtb, rel, attnb, scales);
    qact_k<<<2048, 256, 0, stream>>>(attnb, 524288, scales, 4);

    // Wo: split-K=2 partials (regionA), combine fused into LN2
    gemm_k<4><<<dim3(8, 32, 2), 256, 0, stream>>>(attnb, wtb + 3145728, nullptr, nullptr, nullptr,
                                                  4096, 1024, 1024, 512, pWo, nullptr, scales, -1);
    ln2comb_k<<<4096, 256, 0, stream>>>(pWo, bo, inputs, ln2s, ln2b, yb, scales);
    qact_k<<<2048, 256, 0, stream>>>(yb, 524288, scales, 5);

    // W1: 4096x4096x1024, gelu epilogue
    gemm_k<2><<<dim3(32, 32), 256, 0, stream>>>(yb, wtb + 4194304, b1, nullptr, nullptr,
                                                4096, 4096, 1024, 1024, nullptr, hb, scales, 6);
    qact_k<<<8192, 256, 0, stream>>>(hb, 2097152, scales, 6);

    // W2: split-K=2 partials (regionB), combine -> out
    gemm_k<4><<<dim3(8, 32, 2), 256, 0, stream>>>(hb, wtb + 8388608, nullptr, nullptr, nullptr,
                                                  4096, 1024, 4096, 2048, pW2, nullptr, scales, -1);
    combo_k<<<4096, 256, 0, stream>>>(pW2, b2, out);
}

// Round 6
// 315.630 us; speedup vs baseline: 3.3534x; 1.0057x over previous
//
#include <hip/hip_runtime.h>
#include <cstdint>

// ---------------------------------------------------------------------------
// TransformerBlock: LN1 -> qdq -> QKV gemms -> attn(relpos bias) -> Wo gemm
//  -> +resid -> LN2 -> W1 gemm -> gelu(tanh) -> W2 gemm.
// R1: hierarchical absmax partials.  R2: swapped-QK^T attn, fused QKV gemm.
// R3: BK=64 swizzled GEMM, split-K Wo/W2, LN2+combine fusion.
// R4: 64B-strided atomic partials (L2 atomics serialize per cache line).
// R5: attn: 4 waves/block on one (b,h) (occ 31->50%), XCD-local grid
//     (blockIdx.x=bh -> all q-tiles of a head on one XCD; K/V L2-resident),
//     bit-exact defer-rescale skip (fr==1.0 -> skip o-mults + frs LDS).
// ---------------------------------------------------------------------------

typedef unsigned short u16;
typedef __bf16 bf16x4 __attribute__((ext_vector_type(4)));
typedef __bf16 bf16x8 __attribute__((ext_vector_type(8)));
typedef float  f32x4  __attribute__((ext_vector_type(4)));

#define MFMA(a, b, c) __builtin_amdgcn_mfma_f32_16x16x32_bf16(a, b, c, 0, 0, 0)

#define NSLOT 13
#define PSPREAD 64       // partial slots per logical scale
#define PSTRIDE 16       // ints between partials (64B -> distinct L2 lines)
#define SLOTSZ (PSPREAD * PSTRIDE)   // 1024 ints per logical slot

__device__ __forceinline__ float bf2f(u16 h) {
    return __uint_as_float(((unsigned)h) << 16);
}
__device__ __forceinline__ u16 f2bf(float f) {   // RNE
    unsigned u = __float_as_uint(f);
    u += 0x7FFFu + ((u >> 16) & 1u);
    return (u16)(u >> 16);
}
__device__ __forceinline__ float qdqv(float v, float s) {
    float q = rintf(v / s);                       // rint = RNE, matches jnp.round
    q = fminf(fmaxf(q, -127.f), 127.f);
    return q * s;
}

// wave-cooperative: reduce the 64 partial absmax ints of `slot` -> scale.
__device__ __forceinline__ float getscale64(const int* scales, int slot) {
    float m = __int_as_float(scales[slot * SLOTSZ + (threadIdx.x & 63) * PSTRIDE]);
#pragma unroll
    for (int o = 32; o > 0; o >>= 1) m = fmaxf(m, __shfl_xor(m, o));
    return fmaxf(m / 127.f, 1e-8f);
}

// global -> LDS direct (16B per lane; LDS dest is wave-uniform base + lane*16)
typedef const __attribute__((address_space(1))) unsigned gas_u32;
typedef __attribute__((address_space(3))) unsigned las_u32;
__device__ __forceinline__ void gld16(const void* g, void* l) {
    __builtin_amdgcn_global_load_lds((gas_u32*)g, (las_u32*)l, 16, 0, 0);
}

// ---------------------------------------------------------------------------
__global__ void zero_k(int* s) {
    const int i = blockIdx.x * 256 + threadIdx.x;
    if (i < NSLOT * SLOTSZ) s[i] = 0;
}

// fused absmax of the six weight tensors -> slots 7..12 (one launch).
__global__ __launch_bounds__(256) void wabsmax6_k(const float* __restrict__ w0, const float* __restrict__ w1,
                                                  const float* __restrict__ w2, const float* __restrict__ w3,
                                                  const float* __restrict__ w4, const float* __restrict__ w5,
                                                  int* scales) {
    const int b = blockIdx.x;
    int ti, boff;
    if (b < 1024)      { ti = b >> 8; boff = (b & 255) * 4096; }
    else if (b < 2048) { ti = 4;      boff = (b - 1024) * 4096; }
    else               { ti = 5;      boff = (b - 2048) * 4096; }
    const float* w = (ti == 0) ? w0 : (ti == 1) ? w1 : (ti == 2) ? w2
                   : (ti == 3) ? w3 : (ti == 4) ? w4 : w5;
    const float4* wv = (const float4*)(w + boff);
    float m = 0.f;
#pragma unroll
    for (int k = 0; k < 4; k++) {
        float4 v = wv[threadIdx.x + k * 256];
        m = fmaxf(m, fmaxf(fmaxf(fabsf(v.x), fabsf(v.y)), fmaxf(fabsf(v.z), fabsf(v.w))));
    }
#pragma unroll
    for (int o = 32; o > 0; o >>= 1) m = fmaxf(m, __shfl_xor(m, o));
    if ((threadIdx.x & 63) == 0)
        atomicMax(scales + (7 + ti) * SLOTSZ + (((b * 4 + (threadIdx.x >> 6)) & (PSPREAD - 1)) * PSTRIDE),
                  __float_as_int(m));
}

// fused quantize+transpose of all six weights: W[K][N] fp32 -> Wt[N][K] bf16.
// wtbase layout: wtq,wtk,wtv,wto (1M u16 each), wt1 (4M), wt2 (4M).
__global__ __launch_bounds__(256) void wqt6_k(const float* __restrict__ w0, const float* __restrict__ w1,
                                              const float* __restrict__ w2, const float* __restrict__ w3,
                                              const float* __restrict__ w4, const float* __restrict__ w5,
                                              u16* __restrict__ wtbase, const int* __restrict__ scales) {
    __shared__ float t[32][33];
    const int b = blockIdx.x;
    const float* W;
    u16* Wt;
    int K, N, bx, by, slot;
    if (b < 4096) {
        const int ti = b >> 10, r = b & 1023;
        W = (ti == 0) ? w0 : (ti == 1) ? w1 : (ti == 2) ? w2 : w3;
        Wt = wtbase + (long)ti * 1048576;
        K = 1024; N = 1024; bx = r & 31; by = r >> 5; slot = 7 + ti;
    } else if (b < 8192) {
        const int r = b - 4096;
        W = w4; Wt = wtbase + 4194304;
        K = 1024; N = 4096; bx = r & 127; by = r >> 7; slot = 11;
    } else {
        const int r = b - 8192;
        W = w5; Wt = wtbase + 8388608;
        K = 4096; N = 1024; bx = r & 31; by = r >> 5; slot = 12;
    }
    const int n0 = bx * 32, k0 = by * 32;
    const float s = getscale64(scales, slot);
    const int c = threadIdx.x & 31, r0 = threadIdx.x >> 5;
#pragma unroll
    for (int i = 0; i < 4; i++) {
        int kk = k0 + r0 + i * 8;
        t[r0 + i * 8][c] = qdqv(W[(long)kk * N + n0 + c], s);
    }
    __syncthreads();
#pragma unroll
    for (int i = 0; i < 4; i++) {
        int nn = n0 + r0 + i * 8;
        Wt[(long)nn * K + k0 + c] = f2bf(t[c][r0 + i * 8]);
    }
}

// block reduction helper (256 threads, 4 waves)
__device__ __forceinline__ float blk_sum(float v, float* red) {
#pragma unroll
    for (int o = 32; o > 0; o >>= 1) v += __shfl_xor(v, o);
    __syncthreads();
    if ((threadIdx.x & 63) == 0) red[threadIdx.x >> 6] = v;
    __syncthreads();
    return red[0] + red[1] + red[2] + red[3];
}

// block absmax commit: one atomic per block (line-strided partial slot)
__device__ __forceinline__ void blk_absmax_commit(float am, float* red, int* scales, int slot) {
#pragma unroll
    for (int o = 32; o > 0; o >>= 1) am = fmaxf(am, __shfl_xor(am, o));
    __syncthreads();                              // red[] reuse safety
    if ((threadIdx.x & 63) == 0) red[threadIdx.x >> 6] = am;
    __syncthreads();
    if (threadIdx.x == 0) {
        float m = fmaxf(fmaxf(red[0], red[1]), fmaxf(red[2], red[3]));
        atomicMax(scales + slot * SLOTSZ + ((blockIdx.x & (PSPREAD - 1)) * PSTRIDE),
                  __float_as_int(m));
    }
}

// LayerNorm (eps=1e-6): fp32 in -> bf16 out (raw, pre-qdq), absmax -> slot
__global__ __launch_bounds__(256) void ln_k(const float* __restrict__ in, const float* __restrict__ gam,
                                            const float* __restrict__ bet, u16* __restrict__ out,
                                            int* __restrict__ scales, int slot) {
    __shared__ float red[4];
    const long row = blockIdx.x;
    const int tid = threadIdx.x;
    float4 v = ((const float4*)(in + row * 1024))[tid];
    float mean = blk_sum(v.x + v.y + v.z + v.w, red) * (1.f / 1024.f);
    float dx = v.x - mean, dy = v.y - mean, dz = v.z - mean, dw = v.w - mean;
    float var = blk_sum(dx * dx + dy * dy + dz * dz + dw * dw, red) * (1.f / 1024.f);
    float inv = rsqrtf(var + 1e-6f);
    float4 gg = ((const float4*)gam)[tid];
    float4 bb = ((const float4*)bet)[tid];
    float o0 = dx * inv * gg.x + bb.x, o1 = dy * inv * gg.y + bb.y;
    float o2 = dz * inv * gg.z + bb.z, o3 = dw * inv * gg.w + bb.w;
    ushort4 st;
    st.x = f2bf(o0); st.y = f2bf(o1); st.z = f2bf(o2); st.w = f2bf(o3);
    ((ushort4*)(out + row * 1024))[tid] = st;
    float am = fmaxf(fmaxf(fabsf(o0), fabsf(o1)), fmaxf(fabsf(o2), fabsf(o3)));
    blk_absmax_commit(am, red, scales, slot);
}

// Wo-combine + residual + LayerNorm2 fused: v = p0+p1+bo+inputs, LN -> yb.
__global__ __launch_bounds__(256) void ln2comb_k(const float* __restrict__ p, const float* __restrict__ bo,
                                                 const float* __restrict__ inputs,
                                                 const float* __restrict__ gam, const float* __restrict__ bet,
                                                 u16* __restrict__ out, int* __restrict__ scales) {
    __shared__ float red[4];
    const long row = blockIdx.x;
    const int tid = threadIdx.x;
    float4 a = ((const float4*)(p + row * 1024))[tid];
    float4 b = ((const float4*)(p + 4194304 + row * 1024))[tid];
    float4 bb0 = ((const float4*)bo)[tid];
    float4 xi = ((const float4*)(inputs + row * 1024))[tid];
    float4 v;
    v.x = a.x + b.x + bb0.x + xi.x; v.y = a.y + b.y + bb0.y + xi.y;
    v.z = a.z + b.z + bb0.z + xi.z; v.w = a.w + b.w + bb0.w + xi.w;
    float mean = blk_sum(v.x + v.y + v.z + v.w, red) * (1.f / 1024.f);
    float dx = v.x - mean, dy = v.y - mean, dz = v.z - mean, dw = v.w - mean;
    float var = blk_sum(dx * dx + dy * dy + dz * dz + dw * dw, red) * (1.f / 1024.f);
    float inv = rsqrtf(var + 1e-6f);
    float4 gg = ((const float4*)gam)[tid];
    float4 bb = ((const float4*)bet)[tid];
    float o0 = dx * inv * gg.x + bb.x, o1 = dy * inv * gg.y + bb.y;
    float o2 = dz * inv * gg.z + bb.z, o3 = dw * inv * gg.w + bb.w;
    ushort4 st;
    st.x = f2bf(o0); st.y = f2bf(o1); st.z = f2bf(o2); st.w = f2bf(o3);
    ((ushort4*)(out + row * 1024))[tid] = st;
    float am = fmaxf(fmaxf(fabsf(o0), fabsf(o1)), fmaxf(fabsf(o2), fabsf(o3)));
    blk_absmax_commit(am, red, scales, 5);
}

// W2-combine: out = p0 + p1 + b2   (4M floats, final output)
__global__ void combo_k(const float* __restrict__ p, const float* __restrict__ b2,
                        float* __restrict__ out) {
    const int i = blockIdx.x * 256 + threadIdx.x;   // float4 index, 1M total
    float4 a = ((const float4*)p)[i];
    float4 b = ((const float4*)(p + 4194304))[i];
    float4 bb = ((const float4*)b2)[i & 255];
    float4 o;
    o.x = a.x + b.x + bb.x; o.y = a.y + b.y + bb.y;
    o.z = a.z + b.z + bb.z; o.w = a.w + b.w + bb.w;
    ((float4*)out)[i] = o;
}

// in-place elementwise qdq on a bf16 buffer (8 elems / thread)
__global__ void qact_k(u16* buf, int n8, const int* __restrict__ scales, int slot) {
    const float s = getscale64(scales, slot);     // uniform, before any early-out
    int i = blockIdx.x * 256 + threadIdx.x;
    if (i >= n8) return;
    uint4 u = ((const uint4*)buf)[i];
    unsigned w[4] = {u.x, u.y, u.z, u.w};
#pragma unroll
    for (int j = 0; j < 4; j++) {
        float lo = qdqv(bf2f((u16)(w[j] & 0xFFFFu)), s);
        float hi = qdqv(bf2f((u16)(w[j] >> 16)), s);
        w[j] = (unsigned)f2bf(lo) | ((unsigned)f2bf(hi) << 16);
    }
    uint4 o; o.x = w[0]; o.y = w[1]; o.z = w[2]; o.w = w[3];
    ((uint4*)buf)[i] = o;
}

// q and k buffers in one launch (contiguous; slots 1,2). grid 4096.
__global__ void qact2_k(u16* buf, const int* __restrict__ scales) {
    const int i = blockIdx.x * 256 + threadIdx.x;       // uint4 index
    const int slot = (i >= 524288) ? 2 : 1;             // block-uniform
    const float s = getscale64(scales, slot);
    uint4 u = ((const uint4*)buf)[i];
    unsigned w[4] = {u.x, u.y, u.z, u.w};
#pragma unroll
    for (int j = 0; j < 4; j++) {
        float lo = qdqv(bf2f((u16)(w[j] & 0xFFFFu)), s);
        float hi = qdqv(bf2f((u16)(w[j] >> 16)), s);
        w[j] = (unsigned)f2bf(lo) | ((unsigned)f2bf(hi) << 16);
    }
    uint4 o; o.x = w[0]; o.y = w[1]; o.z = w[2]; o.w = w[3];
    ((uint4*)buf)[i] = o;
}

// qdq + transpose V: v[B*H][S][32] bf16 -> vt[B*H][32][S] bf16
__global__ __launch_bounds__(256) void vtrans_k(const u16* __restrict__ v, u16* __restrict__ vt,
                                                const int* __restrict__ scales) {
    __shared__ u16 t[32][33];
    const int bh = blockIdx.y, s0 = blockIdx.x * 32;
    const float s = getscale64(scales, 3);
    const int c = threadIdx.x & 31, r0 = threadIdx.x >> 5;
    const u16* src = v + ((long)bh * 1024 + s0) * 32;
#pragma unroll
    for (int i = 0; i < 4; i++) {
        int r = r0 + i * 8;
        t[r][c] = f2bf(qdqv(bf2f(src[r * 32 + c]), s));
    }
    __syncthreads();
    u16* dst = vt + (long)bh * 32768;
#pragma unroll
    for (int i = 0; i < 4; i++) {
        int r = r0 + i * 8;                       // d index
        dst[(long)r * 1024 + s0 + c] = t[c][r];
    }
}

// ---------------------------------------------------------------------------
// GEMM: C[M][N] = A[M][K](bf16) * Bt[N][K](bf16)^T, 128x128 tile, BK=64,
// 256 threads (2x2 waves). LDS XOR-swizzle (rule-21): linear gld16 dest,
// inverse-swizzled global source, swizzled ds_read -> conflict-free b128.
// EPI 0: QKV (blockIdx.z = tensor), scatter [B,H,S,HD] bf16 + absmax
// EPI 2: gelu(tanh) -> bf16 + absmax           (W1)
// EPI 4: split-K partial (blockIdx.z = k-slice), raw fp32, no bias
// ---------------------------------------------------------------------------
template <int EPI>
__global__ __launch_bounds__(256, 2) void gemm_k(const u16* __restrict__ A, const u16* __restrict__ Bt,
                                                 const float* __restrict__ bias, const float* __restrict__ bias2,
                                                 const float* __restrict__ bias3,
                                                 int M, int N, int Kfull, int Kslice,
                                                 float* __restrict__ outf, u16* __restrict__ outb,
                                                 int* __restrict__ scales, int slot) {
    __shared__ u16 As[128 * 64];                  // 16KB
    __shared__ u16 Bs[128 * 64];                  // 16KB
    const float* bp = bias;
    long koff = 0, ooff = 0;
    if (EPI == 0) {
        const int z = blockIdx.z;
        Bt += (long)z * 1048576;                  // wtq/wtk/wtv contiguous
        outb += (long)z * 4194304;                // qb/kb/vb contiguous
        bp = (z == 0) ? bias : (z == 1 ? bias2 : bias3);
        slot += z;
    }
    if (EPI == 4) {
        koff = (long)blockIdx.z * Kslice * 2;     // byte offset into K
        ooff = (long)blockIdx.z * M * N;          // partial-buffer offset
    }
    const int tid = threadIdx.x;
    const int lane = tid & 63;
    const int wave = tid >> 6;
    const int wm = wave >> 1, wn = wave & 1;
    const int bm = blockIdx.y * 128, bn = blockIdx.x * 128;
    const int g = lane >> 4, c = lane & 15;

    const long astride = (long)Kfull * 2;         // bytes per row
    // staging: 8 lanes per 128B row-chunk; source pre-swizzled so linear LDS
    // dest yields XOR-swizzled layout (involution: cb ^ ((row&7)<<4)).
    const int srow = wave * 32 + (lane >> 3);
    const int scol = ((lane & 7) * 16) ^ ((lane >> 3) << 4);
    const char* Ag = (const char*)A + (long)(bm + srow) * astride + scol + koff;
    const char* Bg = (const char*)Bt + (long)(bn + srow) * astride + scol + koff;
    char* Al = (char*)As + wave * 4096;           // wave-uniform LDS dest
    char* Bl = (char*)Bs + wave * 4096;

    f32x4 acc[4][4];
    const f32x4 zf = {0.f, 0.f, 0.f, 0.f};
#pragma unroll
    for (int i = 0; i < 4; i++)
#pragma unroll
        for (int j = 0; j < 4; j++) acc[i][j] = zf;

    const int nk = Kslice >> 6;
    for (int kt = 0; kt < nk; ++kt) {
        __syncthreads();                          // protect LDS from prior reads
        const long ko = (long)kt * 128;
#pragma unroll
        for (int i = 0; i < 4; i++) gld16(Ag + ko + (long)(i * 8) * astride, Al + i * 1024);
#pragma unroll
        for (int i = 0; i < 4; i++) gld16(Bg + ko + (long)(i * 8) * astride, Bl + i * 1024);
        __syncthreads();                          // vmcnt(0) drain before barrier

#pragma unroll
        for (int kh = 0; kh < 2; kh++) {
            bf16x8 af[4], bq[4];
            const int kb = kh * 64 + g * 16;
            const int sw = kb ^ ((c & 7) << 4);   // swizzled read offset
#pragma unroll
            for (int i = 0; i < 4; i++)
                af[i] = *(const bf16x8*)((const char*)As + (wm * 64 + i * 16 + c) * 128 + sw);
#pragma unroll
            for (int j = 0; j < 4; j++)
                bq[j] = *(const bf16x8*)((const char*)Bs + (wn * 64 + j * 16 + c) * 128 + sw);
#pragma unroll
            for (int i = 0; i < 4; i++)
#pragma unroll
                for (int j = 0; j < 4; j++)
                    acc[i][j] = MFMA(af[i], bq[j], acc[i][j]);
        }
    }

    float am = 0.f;
#pragma unroll
    for (int i = 0; i < 4; i++) {
#pragma unroll
        for (int j = 0; j < 4; j++) {
#pragma unroll
            for (int t = 0; t < 4; t++) {
                const int row = bm + wm * 64 + i * 16 + g * 4 + t;
                const int col = bn + wn * 64 + j * 16 + c;
                if (EPI == 0) {
                    float v = acc[i][j][t] + bp[col];
                    // [B*S][H*HD] -> [B,H,S,HD]
                    long oi = ((long)((row >> 10) * 32 + (col >> 5))) * 32768
                              + (long)(row & 1023) * 32 + (col & 31);
                    outb[oi] = f2bf(v);
                    am = fmaxf(am, fabsf(v));
                } else if (EPI == 2) {
                    float v = acc[i][j][t] + bp[col];
                    float t3 = v * v * v;
                    float gl = 0.5f * v * (1.f + tanhf(0.79788456080286536f * (v + 0.044715f * t3)));
                    outb[(long)row * N + col] = f2bf(gl);
                    am = fmaxf(am, fabsf(gl));
                } else {                          // EPI 4: raw partial
                    outf[ooff + (long)row * N + col] = acc[i][j][t];
                }
            }
        }
    }
    if (EPI == 0 || EPI == 2) {
#pragma unroll
        for (int o = 32; o > 0; o >>= 1) am = fmaxf(am, __shfl_xor(am, o));
        if (lane == 0)
            atomicMax(scales + slot * SLOTSZ
                          + ((((blockIdx.x + blockIdx.y * gridDim.x) * 4 + wave) & (PSPREAD - 1)) * PSTRIDE),
                      __float_as_int(am));
    }
}

// ---------------------------------------------------------------------------
// Attention v3 (R5): 4 waves/block, each wave one 32-q tile of the SAME bh
// (K/V shared via L1/L2). blockIdx.x = bh -> all blocks of a head on one XCD
// (flat%8 = bh%8), K/V L2-resident. Swapped QK^T, lane-local softmax,
// uniform-rel-bias fast path, bit-exact defer-rescale skip.
// ---------------------------------------------------------------------------
__global__ __launch_bounds__(256) void attn_k(const u16* __restrict__ q, const u16* __restrict__ k,
                                              const u16* __restrict__ vt, const float* __restrict__ relpos,
                                              u16* __restrict__ attn, int* __restrict__ scales) {
    __shared__ float rel_s[65];                   // rel[d]*scale for this head
    __shared__ u16 P[4][32 * 40];                 // per-wave P tile, padded
    __shared__ float frs[4][32];                  // per-wave fr / l transfer
    const int tid = threadIdx.x;
    const int lane = tid & 63;
    const int w = tid >> 6;
    const int bh = blockIdx.x;                    // fastest-varying -> XCD-local
    const int b = bh >> 5, h = bh & 31;
    const int q0 = blockIdx.y * 128 + w * 32;
    const int g = lane >> 4, c = lane & 15;
    const float SC = 0.03125f;                    // 1/(sqrt(32)*1024^0.25)
    for (int i = tid; i < 65; i += 256) rel_s[i] = relpos[i * 32 + h] * SC;
    __syncthreads();
    const float rb0 = rel_s[0], rb64 = rel_s[64];

    const u16* qb = q + ((long)bh * 1024 + q0) * 32;
    const u16* kb = k + (long)bh * 32768;
    const u16* vb = vt + (long)bh * 32768;
    u16* Pw = P[w];
    float* fw = frs[w];

    bf16x8 aq[2];                                 // Q as B-fragment: col=q, k=d
#pragma unroll
    for (int i = 0; i < 2; i++) aq[i] = *(const bf16x8*)(qb + (i * 16 + c) * 32 + g * 8);

    const f32x4 zf = {0.f, 0.f, 0.f, 0.f};
    f32x4 o[2][2] = {{zf, zf}, {zf, zf}};         // row=q(g*4+t), col=d(j*16+c)
    float m_run[2] = {-1e30f, -1e30f};            // per q=i*16+c (replicated x4 g)
    float l_run[2] = {0.f, 0.f};

    for (int kt = 0; kt < 32; ++kt) {
        const int kk = kt * 32;
        bf16x8 bk0 = *(const bf16x8*)(kb + (kk + c) * 32 + g * 8);
        bf16x8 bk1 = *(const bf16x8*)(kb + (kk + 16 + c) * 32 + g * 8);
        bf16x8 bv0 = *(const bf16x8*)(vb + c * 1024 + kk + g * 8);
        bf16x8 bv1 = *(const bf16x8*)(vb + (16 + c) * 1024 + kk + g * 8);
        const int mode = (kk >= q0 + 64) ? 0 : (kk <= q0 - 64) ? 1 : 2;

        float frv[2];
#pragma unroll
        for (int i = 0; i < 2; i++) {
            f32x4 s0 = MFMA(bk0, aq[i], zf);      // lane: q=i*16+c, k=kk+g*4+t
            f32x4 s1 = MFMA(bk1, aq[i], zf);      // k=kk+16+g*4+t
            float v[8];
            if (mode == 0) {
#pragma unroll
                for (int t = 0; t < 4; t++) { v[t] = fmaf(s0[t], SC, rb0); v[4 + t] = fmaf(s1[t], SC, rb0); }
            } else if (mode == 1) {
#pragma unroll
                for (int t = 0; t < 4; t++) { v[t] = fmaf(s0[t], SC, rb64); v[4 + t] = fmaf(s1[t], SC, rb64); }
            } else {
                const int base = (q0 + i * 16 + c) - kk - g * 4 + 32;
#pragma unroll
                for (int t = 0; t < 4; t++) {
                    int d0 = min(max(base - t, 0), 64);
                    int d1 = min(max(base - 16 - t, 0), 64);
                    v[t] = fmaf(s0[t], SC, rel_s[d0]);
                    v[4 + t] = fmaf(s1[t], SC, rel_s[d1]);
                }
            }
            float mt = fmaxf(fmaxf(fmaxf(v[0], v[1]), fmaxf(v[2], v[3])),
                             fmaxf(fmaxf(v[4], v[5]), fmaxf(v[6], v[7])));
            mt = fmaxf(mt, __shfl_xor(mt, 16));
            mt = fmaxf(mt, __shfl_xor(mt, 32));
            const float mn = fmaxf(m_run[i], mt);
            const float fr = __expf(m_run[i] - mn);
            frv[i] = fr;
            float sm = 0.f;
            bf16x4 pk0, pk1;
#pragma unroll
            for (int t = 0; t < 4; t++) {
                float p = __expf(v[t] - mn);     sm += p; pk0[t] = (__bf16)p;
                float p2 = __expf(v[4 + t] - mn); sm += p2; pk1[t] = (__bf16)p2;
            }
            sm += __shfl_xor(sm, 16);
            sm += __shfl_xor(sm, 32);
            l_run[i] = l_run[i] * fr + sm;        // fr==1 exact when m unchanged
            m_run[i] = mn;
            *(bf16x4*)&Pw[(i * 16 + c) * 40 + g * 4] = pk0;
            *(bf16x4*)&Pw[(i * 16 + c) * 40 + 16 + g * 4] = pk1;
        }
        // defer-rescale: if every lane's fr is exactly 1.0, o *= 1 is a no-op
        // -> skip the 16 mults and the frs LDS round-trip (bit-exact).
        if (__any((frv[0] != 1.f) | (frv[1] != 1.f))) {
            if (g == 0) { fw[c] = frv[0]; fw[16 + c] = frv[1]; }
            float4 f0 = *(float4*)&fw[g * 4];
            float4 f1 = *(float4*)&fw[16 + g * 4];
#pragma unroll
            for (int j = 0; j < 2; j++) {
                o[0][j][0] *= f0.x; o[0][j][1] *= f0.y; o[0][j][2] *= f0.z; o[0][j][3] *= f0.w;
                o[1][j][0] *= f1.x; o[1][j][1] *= f1.y; o[1][j][2] *= f1.z; o[1][j][3] *= f1.w;
            }
        }
        bf16x8 ap0 = *(const bf16x8*)&Pw[c * 40 + g * 8];
        bf16x8 ap1 = *(const bf16x8*)&Pw[(16 + c) * 40 + g * 8];
        o[0][0] = MFMA(ap0, bv0, o[0][0]);
        o[0][1] = MFMA(ap0, bv1, o[0][1]);
        o[1][0] = MFMA(ap1, bv0, o[1][0]);
        o[1][1] = MFMA(ap1, bv1, o[1][1]);
    }

    if (g == 0) { fw[c] = l_run[0]; fw[16 + c] = l_run[1]; }
    float4 l0 = *(float4*)&fw[g * 4];
    float4 l1 = *(float4*)&fw[16 + g * 4];
    float lv[2][4] = {{l0.x, l0.y, l0.z, l0.w}, {l1.x, l1.y, l1.z, l1.w}};
    float am = 0.f;
#pragma unroll
    for (int i = 0; i < 2; i++)
#pragma unroll
        for (int j = 0; j < 2; j++)
#pragma unroll
            for (int t = 0; t < 4; t++) {
                float val = o[i][j][t] / (lv[i][t] + 1e-6f);
                long row = (long)b * 1024 + q0 + i * 16 + g * 4 + t;
                attn[row * 1024 + h * 32 + j * 16 + c] = f2bf(val);
                am = fmaxf(am, fabsf(val));
            }
#pragma unroll
    for (int o2 = 32; o2 > 0; o2 >>= 1) am = fmaxf(am, __shfl_xor(am, o2));
    if (lane == 0)
        atomicMax(scales + 4 * SLOTSZ + ((((bh * 8 + blockIdx.y) * 4 + w) & (PSPREAD - 1)) * PSTRIDE),
                  __float_as_int(am));
}

// ---------------------------------------------------------------------------
extern "C" void kernel_launch(void* const* d_in, const int* in_sizes, int n_in,
                              void* d_out, int out_size, void* d_ws, size_t ws_size,
                              hipStream_t stream) {
    (void)in_sizes; (void)n_in; (void)out_size; (void)ws_size;
    const float* inputs = (const float*)d_in[0];
    const float* ln1s   = (const float*)d_in[1];
    const float* ln1b   = (const float*)d_in[2];
    const float* Wq     = (const float*)d_in[3];
    const float* bq     = (const float*)d_in[4];
    const float* Wk     = (const float*)d_in[5];
    const float* bk     = (const float*)d_in[6];
    const float* Wv     = (const float*)d_in[7];
    const float* bv     = (const float*)d_in[8];
    const float* rel    = (const float*)d_in[9];
    const float* Wo     = (const float*)d_in[10];
    const float* bo     = (const float*)d_in[11];
    const float* ln2s   = (const float*)d_in[12];
    const float* ln2b   = (const float*)d_in[13];
    const float* W1     = (const float*)d_in[14];
    const float* b1     = (const float*)d_in[15];
    const float* W2     = (const float*)d_in[16];
    const float* b2     = (const float*)d_in[17];
    float* out = (float*)d_out;

    // workspace layout (88 MB + 64 KB), time-multiplexed:
    //  scales: 64 KB (13 slots x 64 partials x 64B line-stride)
    //  regionA (32MB): q/k/v/vt  ->  Wo partials (2x16MB)  ->  h (32MB)
    //  regionB (32MB): xq/attnb(8) + y(8) + spare  ->  W2 partials (2x16MB)
    //  regionC (24MB): wtq,wtk,wtv,wto (2MB ea), wt1 (8MB), wt2 (8MB)
    char* ws = (char*)d_ws;
    int* scales = (int*)ws;
    char* regionA = ws + 65536;
    char* regionB = regionA + (32u << 20);
    char* regionC = regionB + (32u << 20);
    u16* qb    = (u16*)regionA;
    u16* kbuf  = qb + 4194304;
    u16* vbuf  = kbuf + 4194304;
    u16* vtb   = vbuf + 4194304;
    float* pWo = (float*)regionA;          // after attn: q/k/v/vt dead
    u16* hb    = (u16*)regionA;            // after ln2comb: partials dead
    u16* xq    = (u16*)regionB;
    u16* attnb = xq;                       // xq dead after QKV gemm
    u16* yb    = xq + 4194304;
    float* pW2 = (float*)regionB;          // after W1 gemm: xq/yb dead
    u16* wtb   = (u16*)regionC;            // wtq..wt2 contiguous

    // slots: 0=x 1=q 2=k 3=v 4=attn 5=y 6=h 7..12=Wq,Wk,Wv,Wo,W1,W2
    zero_k<<<52, 256, 0, stream>>>(scales);
    wabsmax6_k<<<3072, 256, 0, stream>>>(Wq, Wk, Wv, Wo, W1, W2, scales);

    ln_k<<<4096, 256, 0, stream>>>(inputs, ln1s, ln1b, xq, scales, 0);

    wqt6_k<<<12288, 256, 0, stream>>>(Wq, Wk, Wv, Wo, W1, W2, wtb, scales);

    qact_k<<<2048, 256, 0, stream>>>(xq, 524288, scales, 0);

    // fused QKV: blockIdx.z picks weight/bias/out/slot
    gemm_k<0><<<dim3(8, 32, 3), 256, 0, stream>>>(xq, wtb, bq, bk, bv, 4096, 1024, 1024, 1024,
                                                  nullptr, qb, scales, 1);

    qact2_k<<<4096, 256, 0, stream>>>(qb, scales);          // q (slot1) + k (slot2)
    vtrans_k<<<dim3(32, 128), 256, 0, stream>>>(vbuf, vtb, scales);

    // 4 waves/block (4 q-tiles of one bh); blockIdx.x = bh for XCD locality
    attn_k<<<dim3(128, 8), 256, 0, stream>>>(qb, kbuf, vtb, rel, attnb, scales);
    qact_k<<<2048, 256, 0, stream>>>(attnb, 524288, scales, 4);

    // Wo: split-K=2 partials (regionA), combine fused into LN2
    gemm_k<4><<<dim3(8, 32, 2), 256, 0, stream>>>(attnb, wtb + 3145728, nullptr, nullptr, nullptr,
                                                  4096, 1024, 1024, 512, pWo, nullptr, scales, -1);
    ln2comb_k<<<4096, 256, 0, stream>>>(pWo, bo, inputs, ln2s, ln2b, yb, scales);
    qact_k<<<2048, 256, 0, stream>>>(yb, 524288, scales, 5);

    // W1: 4096x4096x1024, gelu epilogue
    gemm_k<2><<<dim3(32, 32), 256, 0, stream>>>(yb, wtb + 4194304, b1, nullptr, nullptr,
                                                4096, 4096, 1024, 1024, nullptr, hb, scales, 6);
    qact_k<<<8192, 256, 0, stream>>>(hb, 2097152, scales, 6);

    // W2: split-K=2 partials (regionB), combine -> out
    gemm_k<4><<<dim3(8, 32, 2), 256, 0, stream>>>(hb, wtb + 8388608, nullptr, nullptr, nullptr,
                                                  4096, 1024, 4096, 2048, pW2, nullptr, scales, -1);
    combo_k<<<4096, 256, 0, stream>>>(pW2, b2, out);
}